// Round 3
// baseline (402.193 us; speedup 1.0000x reference)
//
#include <hip/hip_runtime.h>
#include <hip/hip_bf16.h>
#include <math.h>

typedef short short8 __attribute__((ext_vector_type(8)));
typedef float f32x4  __attribute__((ext_vector_type(4)));

__device__ __forceinline__ unsigned short f2b(float f) {
  union { float f; unsigned int u; } x; x.f = f;
  return (unsigned short)((x.u + 0x7FFFu + ((x.u >> 16) & 1u)) >> 16);
}
__device__ __forceinline__ float b2f_u(unsigned short u) {
  union { unsigned int u; float f; } x; x.u = ((unsigned int)u) << 16;
  return x.f;
}
// packed f32x2 -> bf16x2 (v_cvt_pk_bf16_f32, RTNE)
__device__ __forceinline__ unsigned int pkbf(float a, float b) {
  union { __hip_bfloat162 h; unsigned int u; } c;
  c.h = __float22bfloat162_rn(make_float2(a, b));
  return c.u;
}
__device__ __forceinline__ float sigm(float x) {
  return __builtin_amdgcn_rcpf(1.f + __expf(-x));
}
__device__ __forceinline__ float tanhfast(float x) {
  float ax = fabsf(x);
  float em = __expf(-2.f * ax);
  float t  = (1.f - em) * __builtin_amdgcn_rcpf(1.f + em);
  return copysignf(t, x);
}
__device__ __forceinline__ float eluf(float v) {
  return v > 0.f ? v : (__expf(v) - 1.f);
}

// ---------------------------------------------------------------------------
// Prepack (unchanged).
// ---------------------------------------------------------------------------
__global__ __launch_bounds__(256) void prepack_kernel(
    const float* __restrict__ Wf,
    const float* __restrict__ Wc, const float* __restrict__ Wn,
    const float* __restrict__ as_c, const float* __restrict__ ad_c,
    const float* __restrict__ as_n, const float* __restrict__ ad_n,
    const float* __restrict__ Wproj,
    const float* __restrict__ Wih_f, const float* __restrict__ Wih_b,
    const float* __restrict__ Wout,
    const float* __restrict__ Whh_f, const float* __restrict__ Whh_b,
    unsigned short* __restrict__ fragB,
    unsigned short* __restrict__ fragWB,
    float* __restrict__ Wa,
    unsigned short* __restrict__ fragP,
    unsigned short* __restrict__ fragIH,
    unsigned short* __restrict__ fragO,
    unsigned short* __restrict__ fragHH)
{
  int e = blockIdx.x * 256 + threadIdx.x;
  unsigned short tmp[8];
  if (e < 4096) {
    int kb = e >> 9, tile = (e >> 6) & 7, lane = e & 63;
    int n = tile * 16 + (lane & 15);
    int kbase = kb * 32 + (lane >> 4) * 8;
#pragma unroll
    for (int j = 0; j < 8; j++) tmp[j] = f2b(Wf[(kbase + j) * 128 + n]);
    *(short8*)(fragB + e * 8) = *(short8*)tmp;
  } else if (e < 5120) {
    int i = e - 4096;
    int s = i >> 9, tile = (i >> 6) & 7, lane = i & 63;
    int c15 = lane & 15, quad = lane >> 4;
    int n = tile * 16 + c15;
    int h = n >> 5, o = n & 31;
    const float* W = s ? Wn : Wc;
#pragma unroll
    for (int j = 0; j < 8; j++) {
      int k = quad * 8 + j;
      tmp[j] = ((k >> 2) == h) ? f2b(W[h * 128 + (k & 3) * 32 + o])
                               : (unsigned short)0;
    }
    *(short8*)(fragWB + i * 8) = *(short8*)tmp;
  } else if (e < 5184) {
    int i = e - 5120;
    int s = i >> 5, d = (i >> 4) & 1, h = (i >> 2) & 3, f = i & 3;
    const float* W = s ? Wn : Wc;
    const float* a = s ? (d ? ad_n : as_n) : (d ? ad_c : as_c);
    float acc = 0.f;
#pragma unroll
    for (int o = 0; o < 32; o++) acc += W[h * 128 + f * 32 + o] * a[h * 32 + o];
    Wa[i] = acc;
  } else if (e < 6208) {
    int i = e - 5184;
    int kb = i >> 8, nt = (i >> 6) & 3, lane = i & 63;
    int c15 = lane & 15, quad = lane >> 4;
#pragma unroll
    for (int j = 0; j < 8; j++)
      tmp[j] = f2b(Wproj[(kb * 32 + quad * 8 + j) * 64 + nt * 16 + c15]);
    *(short8*)(fragP + i * 8) = *(short8*)tmp;
  } else if (e < 7744) {
    int i = e - 6208;
    int d = (i >= 768), r = i - d * 768;
    int kb = r / 384, nt = (r >> 6) % 6, lane = r & 63;
    int c15 = lane & 15, quad = lane >> 4;
    const float* W = d ? Wih_b : Wih_f;
#pragma unroll
    for (int j = 0; j < 8; j++)
      tmp[j] = f2b(W[(kb * 32 + quad * 8 + j) * 96 + nt * 16 + c15]);
    *(short8*)(fragIH + i * 8) = *(short8*)tmp;
  } else if (e < 9280) {
    int r = e - 7744;
    int kb = r >> 8, nt = (r >> 6) & 3, lane = r & 63;
    int c15 = lane & 15, quad = lane >> 4;
#pragma unroll
    for (int j = 0; j < 8; j++)
      tmp[j] = f2b(Wout[(kb * 32 + quad * 8 + j) * 64 + nt * 16 + c15]);
    *(short8*)(fragO + r * 8) = *(short8*)tmp;
  } else if (e < 10048) {
    int i = e - 9280;
    int d = i / 384, r = i - d * 384;
    int nt = r >> 6, lane = r & 63;
    int c15 = lane & 15, quad = lane >> 4;
    const float* W = d ? Whh_b : Whh_f;
#pragma unroll
    for (int j = 0; j < 8; j++)
      tmp[j] = f2b(W[(quad * 8 + j) * 96 + nt * 16 + c15]);
    *(short8*)(fragHH + i * 8) = *(short8*)tmp;
  }
}

// ---------------------------------------------------------------------------
// Kernel 1: GAT + fuse — PERSISTENT at FULL occupancy. 1792 blocks (7/CU,
// LDS-capped), VGPR capped at 72 via launch_bounds(256,7). Weight DATA is
// re-loaded from L2 each iteration (proven cheap in r0/r1), but all weight
// ADDRESSES are loop-invariant base pointers (hoisted by the compiler), so
// the per-iteration addressing VALU that r2 eliminated stays eliminated
// without the 96-VGPR cost that killed r2's occupancy.
// ---------------------------------------------------------------------------
__global__ __launch_bounds__(256, 7) void gat_fuse_kernel(
    const float* __restrict__ self_f, const float* __restrict__ nbr_f,
    const float* __restrict__ Wa,
    const unsigned short* __restrict__ fragWB,
    const unsigned short* __restrict__ fragB,
    const float* __restrict__ b_fuse,
    unsigned short* __restrict__ embb,
    float* __restrict__ out,
    int npairs)
{
  const int tid = threadIdx.x;
  const int w = tid >> 6, lane = tid & 63, c15 = lane & 15, quad = lane >> 4;

  __shared__ __align__(16) float sxf[2][12][4];
  __shared__ __align__(16) float sWa[64];
  __shared__ float sed[2][2][4][12];
  __shared__ __align__(16) unsigned short sA[2][2][16][24];
  __shared__ __align__(16) unsigned short scatb[2][16][268];
  __shared__ __align__(16) float sbias[128];

  // ---- one-time init ----
  if (tid < 32) ((f32x4*)sbias)[tid] = ((const f32x4*)b_fuse)[tid];
  else if (tid < 48) ((f32x4*)sWa)[tid - 32] = ((const f32x4*)Wa)[tid - 32];
  if (tid >= 128) {           // zero sA pad rows 12-15 (never rewritten)
    int t = tid - 128;
    int g = t >> 6, s = (t >> 5) & 1, i = 12 + ((t >> 3) & 3), cp = t & 7;
    *(unsigned int*)&sA[g][s][i][cp * 2] = 0u;
  }

  const int g_q = w & 1, s_q = w >> 1;
  // loop-invariant weight base pointers (per-lane); offsets below are
  // compile-time constants -> no per-iteration address VALU.
  const unsigned short* __restrict__ pwb3 = fragWB + (s_q * 8 * 64 + lane) * 8;
  const unsigned short* __restrict__ pwb4 = fragB + (2 * w * 64 + lane) * 8;

  const int chunk = (npairs + gridDim.x - 1) / gridDim.x;
  const int start = blockIdx.x * chunk;
  const int end   = min(npairs, start + chunk);
  if (start >= end) return;

  // preload x for first iteration (24 lanes x f32x4 = 2 nodes x 48 floats)
  f32x4 xr = {0.f, 0.f, 0.f, 0.f};
  int xnd = 0, xq = 0;
  if (tid < 24) {
    xnd = (tid >= 12); xq = tid - xnd * 12;
    int nn = start * 2 + xnd, b = nn / 5, slot = nn - b * 5;
    const float* src = slot ? (nbr_f + (b * 4 + slot - 1) * 48)
                            : (self_f + b * 48);
    xr = *(const f32x4*)(src + xq * 4);
  }

  for (int it = start; it < end; ++it) {
    const int n0 = it * 2;
    if (tid < 24) ((f32x4*)&sxf[xnd][0][0])[xq] = xr;
    __syncthreads();                           // barrier A (sxf ready; scatb free)
    if (tid < 24 && it + 1 < end) {            // prefetch next pair's x
      int nn = (it + 1) * 2 + xnd, b = nn / 5, slot = nn - b * 5;
      const float* src = slot ? (nbr_f + (b * 4 + slot - 1) * 48)
                              : (self_f + b * 48);
      xr = *(const f32x4*)(src + xq * 4);
    }

    // ---- phases 1+2 (wave-local softmax): wave w -> (g_q, s_q), lanes 0-47 ----
    if (lane < 48) {
      int h = lane / 12, i = lane - h * 12;
      f32x4 xv  = *(const f32x4*)&sxf[g_q][i][0];
      f32x4 was = *(const f32x4*)&sWa[s_q * 32 + h * 4];
      f32x4 wad = *(const f32x4*)&sWa[s_q * 32 + 16 + h * 4];
      float es = xv[0]*was[0] + xv[1]*was[1] + xv[2]*was[2] + xv[3]*was[3];
      float ed = xv[0]*wad[0] + xv[1]*wad[1] + xv[2]*wad[2] + xv[3]*wad[3];
      sed[g_q][s_q][h][i] = ed;
      int blk3 = (i / 3) * 3;
      float xa0 = 0.f, xa1 = 0.f, xa2 = 0.f, xa3 = 0.f, sum = 0.f;
      if (s_q == 0) {
#pragma unroll
        for (int jj = 0; jj < 3; jj++) {
          int j = blk3 + jj;
          float e = es + sed[g_q][0][h][j];
          e = e > 0.f ? e : 0.2f * e;
          float p = __expf(e);
          sum += p;
          f32x4 xj = *(const f32x4*)&sxf[g_q][j][0];
          xa0 += p * xj[0]; xa1 += p * xj[1];
          xa2 += p * xj[2]; xa3 += p * xj[3];
        }
      } else {
#pragma unroll
        for (int jj = 0; jj < 9; jj++) {
          int j = jj < blk3 ? jj : jj + 3;
          float e = es + sed[g_q][1][h][j];
          e = e > 0.f ? e : 0.2f * e;
          float p = __expf(e);
          sum += p;
          f32x4 xj = *(const f32x4*)&sxf[g_q][j][0];
          xa0 += p * xj[0]; xa1 += p * xj[1];
          xa2 += p * xj[2]; xa3 += p * xj[3];
        }
      }
      float inv = 1.f / sum;
      uint2 pk = make_uint2(pkbf(xa0 * inv, xa1 * inv),
                            pkbf(xa2 * inv, xa3 * inv));
      *(uint2*)&sA[g_q][s_q][i][h * 4] = pk;
    }

    // ---- phase 3 (operand-swapped D^T; weight addresses loop-invariant) ----
    {
      const short8 z8 = {0,0,0,0,0,0,0,0};
      short8 xb = z8;
      if (quad < 2) xb = *(const short8*)&sA[g_q][s_q][c15][quad * 8];
#pragma unroll
      for (int tile = 0; tile < 8; tile++) {
        short8 aw = *(const short8*)(pwb3 + tile * 512);
        f32x4 c = {0.f, 0.f, 0.f, 0.f};
        c = __builtin_amdgcn_mfma_f32_16x16x32_bf16(aw, xb, c, 0, 0, 0);
        uint2 pk = make_uint2(pkbf(eluf(c[0]), eluf(c[1])),
                              pkbf(eluf(c[2]), eluf(c[3])));
        *(uint2*)&scatb[g_q][c15][s_q * 128 + tile * 16 + (quad << 2)] = pk;
      }
    }
    __syncthreads();                           // barrier B (scatb ready)

    // ---- phase 4: fuse GEMM (weight addresses loop-invariant) ----
    {
      f32x4 acc[2][2];
#pragma unroll
      for (int nd = 0; nd < 2; nd++)
#pragma unroll
        for (int tt = 0; tt < 2; tt++) acc[nd][tt] = (f32x4){0.f,0.f,0.f,0.f};
#pragma unroll
      for (int kb = 0; kb < 8; kb++) {
        short8 a0 = *(const short8*)&scatb[0][c15][kb * 32 + (quad << 3)];
        short8 a1 = *(const short8*)&scatb[1][c15][kb * 32 + (quad << 3)];
#pragma unroll
        for (int tt = 0; tt < 2; tt++) {
          short8 bw = *(const short8*)(pwb4 + kb * 4096 + tt * 512);
          acc[0][tt] = __builtin_amdgcn_mfma_f32_16x16x32_bf16(a0, bw, acc[0][tt], 0, 0, 0);
          acc[1][tt] = __builtin_amdgcn_mfma_f32_16x16x32_bf16(a1, bw, acc[1][tt], 0, 0, 0);
        }
      }
      float tot[2][2];
#pragma unroll
      for (int nd = 0; nd < 2; nd++) {
#pragma unroll
        for (int tt = 0; tt < 2; tt++) {
          float p = 0.f;
          if (quad < 3) {
            float bcol = sbias[w * 32 + tt * 16 + c15];
#pragma unroll
            for (int r = 0; r < 4; r++) p += eluf(acc[nd][tt][r] + bcol);
          }
          p += __shfl_xor(p, 16);
          p += __shfl_xor(p, 32);
          tot[nd][tt] = p;
        }
      }
      int ndw = quad >> 1, ttw = quad & 1;
      float val = (ndw ? (ttw ? tot[1][1] : tot[1][0])
                       : (ttw ? tot[0][1] : tot[0][0])) * (1.f / 12.f);
      int node = n0 + ndw;
      int col  = w * 32 + ttw * 16 + c15;
      embb[node * 128 + col] = f2b(val);
      int bq = node / 5;
      if (node == bq * 5) out[bq * 192 + col] = val; // exact f32 passthrough
    }
  }
}

// ---------------------------------------------------------------------------
// Kernel 2: head — unchanged from round 2.
// ---------------------------------------------------------------------------
__global__ __launch_bounds__(256) void head_kernel(
    const unsigned short* __restrict__ embb,
    const float* __restrict__ maskp, const float* __restrict__ dirsp,
    const float* __restrict__ W_proj, const float* __restrict__ b_proj,
    const unsigned short* __restrict__ fragP,
    const unsigned short* __restrict__ fragIH,
    const unsigned short* __restrict__ fragHH,
    const float* __restrict__ bih_f, const float* __restrict__ bhh_f,
    const float* __restrict__ bih_b, const float* __restrict__ bhh_b,
    const unsigned short* __restrict__ fragO,
    const float* __restrict__ b_out,
    float* __restrict__ out)
{
  const int b8 = blockIdx.x * 8;
  const int tid = threadIdx.x;
  const int w = tid >> 6, lane = tid & 63, c15 = lane & 15, quad = lane >> 4;

  __shared__ __align__(16) unsigned short sX[32][72];
  __shared__ __align__(16) unsigned short sgi[2][32][96];
  __shared__ float sH[2][8][32];
  __shared__ __align__(16) unsigned short sHb[2][16][32];
  __shared__ __align__(16) float sgh[2][8][96];
  __shared__ __align__(16) unsigned short sCat[16][200];
  __shared__ __align__(16) float sPB[128];
  __shared__ __align__(16) float sBI[2][96], sBH[2][96];
  __shared__ __align__(16) float sBO[64];

  if (tid < 64) { sPB[tid] = b_proj[tid]; sPB[64 + tid] = W_proj[128 * 64 + tid]; sBO[tid] = b_out[tid]; }
  if (tid < 96) { sBI[0][tid] = bih_f[tid]; sBI[1][tid] = bih_b[tid];
                  sBH[0][tid] = bhh_f[tid]; sBH[1][tid] = bhh_b[tid]; }
  {
    unsigned int* hb = (unsigned int*)sHb;     // 512 dwords
    hb[tid] = 0u; hb[tid + 256] = 0u;
    float* hz = (float*)sH;
    for (int i = tid; i < 512; i += 256) hz[i] = 0.f;
  }
  __syncthreads();                             // B1

  // ---- proj via MFMA (swapped) ----
  {
    const int mt  = w >> 1;
    const int nt0 = (w & 1) * 2;
    const int sloc = mt * 4 + (c15 >> 2);
    const int nbr  = c15 & 3;
    const unsigned short* brow = embb + (((b8 + sloc) * 5) + 1 + nbr) * 128;
    short8 xb[4];
#pragma unroll
    for (int kb = 0; kb < 4; kb++)
      xb[kb] = *(const short8*)(brow + kb * 32 + quad * 8);
    f32x4 acc0 = {0.f,0.f,0.f,0.f}, acc1 = acc0;
#pragma unroll
    for (int kb = 0; kb < 4; kb++) {
      short8 a0 = *(const short8*)(fragP + ((kb * 4 + nt0    ) * 64 + lane) * 8);
      short8 a1 = *(const short8*)(fragP + ((kb * 4 + nt0 + 1) * 64 + lane) * 8);
      acc0 = __builtin_amdgcn_mfma_f32_16x16x32_bf16(a0, xb[kb], acc0, 0, 0, 0);
      acc1 = __builtin_amdgcn_mfma_f32_16x16x32_bf16(a1, xb[kb], acc1, 0, 0, 0);
    }
    const float dirv  = dirsp[(b8 + sloc) * 4 + nbr];
    const float maskv = maskp[(b8 + sloc) * 4 + nbr];
#pragma unroll
    for (int tt = 0; tt < 2; tt++) {
      f32x4 c = tt ? acc1 : acc0;
      int colb = (nt0 + tt) * 16 + (quad << 2);
      f32x4 wp = *(const f32x4*)&sPB[64 + colb];
      f32x4 pb = *(const f32x4*)&sPB[colb];
      float v0 = fmaxf(c[0] + dirv * wp[0] + pb[0], 0.f) * maskv;
      float v1 = fmaxf(c[1] + dirv * wp[1] + pb[1], 0.f) * maskv;
      float v2 = fmaxf(c[2] + dirv * wp[2] + pb[2], 0.f) * maskv;
      float v3 = fmaxf(c[3] + dirv * wp[3] + pb[3], 0.f) * maskv;
      uint2 pk = make_uint2(pkbf(v0, v1), pkbf(v2, v3));
      *(uint2*)&sX[mt * 16 + c15][colb] = pk;
    }
  }
  __syncthreads();                             // B2

  // ---- gi via MFMA + sCat self-emb staging ----
  {
    const int mt  = w >> 1;
    const int ntb = (w & 1) * 3;
    short8 xb0 = *(const short8*)&sX[mt * 16 + c15][quad * 8];
    short8 xb1 = *(const short8*)&sX[mt * 16 + c15][32 + quad * 8];
#pragma unroll
    for (int d = 0; d < 2; d++) {
#pragma unroll
      for (int t2 = 0; t2 < 3; t2++) {
        int nt = ntb + t2;
        f32x4 acc = {0.f,0.f,0.f,0.f};
        short8 a0 = *(const short8*)(fragIH + ((d * 12 +     nt) * 64 + lane) * 8);
        short8 a1 = *(const short8*)(fragIH + ((d * 12 + 6 + nt) * 64 + lane) * 8);
        acc = __builtin_amdgcn_mfma_f32_16x16x32_bf16(a0, xb0, acc, 0, 0, 0);
        acc = __builtin_amdgcn_mfma_f32_16x16x32_bf16(a1, xb1, acc, 0, 0, 0);
        f32x4 bi = *(const f32x4*)&sBI[d][nt * 16 + (quad << 2)];
        uint2 pk = make_uint2(pkbf(acc[0] + bi[0], acc[1] + bi[1]),
                              pkbf(acc[2] + bi[2], acc[3] + bi[3]));
        *(uint2*)&sgi[d][mt * 16 + c15][nt * 16 + (quad << 2)] = pk;
      }
    }
    if (tid >= 128) {                          // stage self_emb -> sCat[:,0:128]
      int t = tid - 128;                       // 0..127
      int s = t >> 4, c8 = (t & 15) * 8;
      short8 v = *(const short8*)(embb + (b8 + s) * 5 * 128 + c8);
      *(short8*)&sCat[s][c8] = v;
    }
  }
  __syncthreads();                             // B3

  // ---- GRU: 4 waves = (dir d = w>>1) x (sample-half q = w&1), 4 samples each.
  {
    const int d = w >> 1;
    const int q = w & 1;
    const int u = lane & 31, sp = lane >> 5;
    for (int step = 0; step < 4; step++) {
      short8 hb = *(const short8*)&sHb[d][c15][quad * 8];
#pragma unroll
      for (int nt = 0; nt < 6; nt++) {
        short8 aw = *(const short8*)(fragHH + ((d * 6 + nt) * 64 + lane) * 8);
        f32x4 c = {0.f,0.f,0.f,0.f};
        c = __builtin_amdgcn_mfma_f32_16x16x32_bf16(aw, hb, c, 0, 0, 0);
        if ((c15 >> 2) == q)                   // own sample rows only
          *(f32x4*)&sgh[d][c15][nt * 16 + (quad << 2)] = c;
      }
      const int k = d ? (3 - step) : step;
#pragma unroll
      for (int si = 0; si < 2; si++) {
        int s = q * 4 + sp + si * 2;
        int row = s * 4 + k;
        float ghr = sgh[d][s][u]      + sBH[d][u];
        float ghz = sgh[d][s][32 + u] + sBH[d][32 + u];
        float ghn = sgh[d][s][64 + u] + sBH[d][64 + u];
        float r = sigm(b2f_u(sgi[d][row][u]) + ghr);
        float z = sigm(b2f_u(sgi[d][row][32 + u]) + ghz);
        float n = tanhfast(b2f_u(sgi[d][row][64 + u]) + r * ghn);
        float h = (1.f - z) * n + z * sH[d][s][u];
        sH[d][s][u] = h;
        sHb[d][s][u] = f2b(h);
        if (step == 3) sCat[s][128 + d * 32 + u] = f2b(h);
      }
    }
  }
  __syncthreads();                             // B4

  // ---- out head via MFMA (swapped) ----
  {
    const int nt = w;
    f32x4 acc = {0.f,0.f,0.f,0.f};
#pragma unroll
    for (int kb = 0; kb < 6; kb++) {
      short8 bb = *(const short8*)&sCat[c15][kb * 32 + quad * 8];
      short8 aw = *(const short8*)(fragO + ((kb * 4 + nt) * 64 + lane) * 8);
      acc = __builtin_amdgcn_mfma_f32_16x16x32_bf16(aw, bb, acc, 0, 0, 0);
    }
    if (c15 < 8) {                             // D[out-col][sample]
      f32x4 bo = *(const f32x4*)&sBO[nt * 16 + (quad << 2)];
      f32x4 v;
      v[0] = fmaxf(acc[0] + bo[0], 0.f);
      v[1] = fmaxf(acc[1] + bo[1], 0.f);
      v[2] = fmaxf(acc[2] + bo[2], 0.f);
      v[3] = fmaxf(acc[3] + bo[3], 0.f);
      *(f32x4*)(out + (b8 + c15) * 192 + 128 + nt * 16 + (quad << 2)) = v;
    }
  }
}

// ---------------------------------------------------------------------------
extern "C" void kernel_launch(void* const* d_in, const int* in_sizes, int n_in,
                              void* d_out, int out_size, void* d_ws, size_t ws_size,
                              hipStream_t stream) {
  const float* self_f  = (const float*)d_in[0];
  const float* nbr_f   = (const float*)d_in[1];
  const float* maskp   = (const float*)d_in[2];
  const float* dirsp   = (const float*)d_in[3];
  const float* W_coop  = (const float*)d_in[4];
  const float* as_coop = (const float*)d_in[5];
  const float* ad_coop = (const float*)d_in[6];
  const float* W_conf  = (const float*)d_in[7];
  const float* as_conf = (const float*)d_in[8];
  const float* ad_conf = (const float*)d_in[9];
  const float* W_fuse  = (const float*)d_in[10];
  const float* b_fuse  = (const float*)d_in[11];
  const float* W_proj  = (const float*)d_in[12];
  const float* b_proj  = (const float*)d_in[13];
  const float* Wih_f   = (const float*)d_in[14];
  const float* Whh_f   = (const float*)d_in[15];
  const float* bih_f   = (const float*)d_in[16];
  const float* bhh_f   = (const float*)d_in[17];
  const float* Wih_b   = (const float*)d_in[18];
  const float* Whh_b   = (const float*)d_in[19];
  const float* bih_b   = (const float*)d_in[20];
  const float* bhh_b   = (const float*)d_in[21];
  const float* W_out   = (const float*)d_in[22];
  const float* b_out   = (const float*)d_in[23];

  const int B = in_sizes[0] / 48;   // 8192
  char* ws = (char*)d_ws;
  unsigned short* fragB  = (unsigned short*)(ws);            // 65536 B
  unsigned short* fragWB = (unsigned short*)(ws + 65536);    // 16384 B
  float*          Wa     = (float*)(ws + 81920);             // 256 B
  unsigned short* fragP  = (unsigned short*)(ws + 82176);    // 16384 B
  unsigned short* fragIH = (unsigned short*)(ws + 98560);    // 24576 B
  unsigned short* fragO  = (unsigned short*)(ws + 123136);   // 24576 B
  unsigned short* fragHH = (unsigned short*)(ws + 147712);   // 12288 B
  unsigned short* embb   = (unsigned short*)(ws + 160000);   // B*5*128*2

  prepack_kernel<<<40, 256, 0, stream>>>(
      W_fuse, W_coop, W_conf, as_coop, ad_coop, as_conf, ad_conf,
      W_proj, Wih_f, Wih_b, W_out, Whh_f, Whh_b,
      fragB, fragWB, Wa, fragP, fragIH, fragO, fragHH);

  const int npairs = B * 5 / 2;   // 20480
  gat_fuse_kernel<<<1792, 256, 0, stream>>>(
      self_f, nbr_f, Wa, fragWB, fragB, b_fuse, embb, (float*)d_out, npairs);

  head_kernel<<<B / 8, 256, 0, stream>>>(
      embb, maskp, dirsp, W_proj, b_proj, fragP, fragIH, fragHH,
      bih_f, bhh_f, bih_b, bhh_b,
      fragO, b_out, (float*)d_out);
}

// Round 4
// 389.238 us; speedup vs baseline: 1.0333x; 1.0333x over previous
//
#include <hip/hip_runtime.h>
#include <hip/hip_bf16.h>
#include <math.h>

typedef short short8 __attribute__((ext_vector_type(8)));
typedef float f32x4  __attribute__((ext_vector_type(4)));

__device__ __forceinline__ unsigned short f2b(float f) {
  union { float f; unsigned int u; } x; x.f = f;
  return (unsigned short)((x.u + 0x7FFFu + ((x.u >> 16) & 1u)) >> 16);
}
__device__ __forceinline__ float b2f_u(unsigned short u) {
  union { unsigned int u; float f; } x; x.u = ((unsigned int)u) << 16;
  return x.f;
}
// packed f32x2 -> bf16x2 (v_cvt_pk_bf16_f32, RTNE)
__device__ __forceinline__ unsigned int pkbf(float a, float b) {
  union { __hip_bfloat162 h; unsigned int u; } c;
  c.h = __float22bfloat162_rn(make_float2(a, b));
  return c.u;
}
__device__ __forceinline__ float sigm(float x) {
  return __builtin_amdgcn_rcpf(1.f + __expf(-x));
}
__device__ __forceinline__ float tanhfast(float x) {
  float ax = fabsf(x);
  float em = __expf(-2.f * ax);
  float t  = (1.f - em) * __builtin_amdgcn_rcpf(1.f + em);
  return copysignf(t, x);
}
__device__ __forceinline__ float eluf(float v) {
  return v > 0.f ? v : (__expf(v) - 1.f);
}

// ---------------------------------------------------------------------------
// Prepack (unchanged).
// ---------------------------------------------------------------------------
__global__ __launch_bounds__(256) void prepack_kernel(
    const float* __restrict__ Wf,
    const float* __restrict__ Wc, const float* __restrict__ Wn,
    const float* __restrict__ as_c, const float* __restrict__ ad_c,
    const float* __restrict__ as_n, const float* __restrict__ ad_n,
    const float* __restrict__ Wproj,
    const float* __restrict__ Wih_f, const float* __restrict__ Wih_b,
    const float* __restrict__ Wout,
    const float* __restrict__ Whh_f, const float* __restrict__ Whh_b,
    unsigned short* __restrict__ fragB,
    unsigned short* __restrict__ fragWB,
    float* __restrict__ Wa,
    unsigned short* __restrict__ fragP,
    unsigned short* __restrict__ fragIH,
    unsigned short* __restrict__ fragO,
    unsigned short* __restrict__ fragHH)
{
  int e = blockIdx.x * 256 + threadIdx.x;
  unsigned short tmp[8];
  if (e < 4096) {
    int kb = e >> 9, tile = (e >> 6) & 7, lane = e & 63;
    int n = tile * 16 + (lane & 15);
    int kbase = kb * 32 + (lane >> 4) * 8;
#pragma unroll
    for (int j = 0; j < 8; j++) tmp[j] = f2b(Wf[(kbase + j) * 128 + n]);
    *(short8*)(fragB + e * 8) = *(short8*)tmp;
  } else if (e < 5120) {
    int i = e - 4096;
    int s = i >> 9, tile = (i >> 6) & 7, lane = i & 63;
    int c15 = lane & 15, quad = lane >> 4;
    int n = tile * 16 + c15;
    int h = n >> 5, o = n & 31;
    const float* W = s ? Wn : Wc;
#pragma unroll
    for (int j = 0; j < 8; j++) {
      int k = quad * 8 + j;
      tmp[j] = ((k >> 2) == h) ? f2b(W[h * 128 + (k & 3) * 32 + o])
                               : (unsigned short)0;
    }
    *(short8*)(fragWB + i * 8) = *(short8*)tmp;
  } else if (e < 5184) {
    int i = e - 5120;
    int s = i >> 5, d = (i >> 4) & 1, h = (i >> 2) & 3, f = i & 3;
    const float* W = s ? Wn : Wc;
    const float* a = s ? (d ? ad_n : as_n) : (d ? ad_c : as_c);
    float acc = 0.f;
#pragma unroll
    for (int o = 0; o < 32; o++) acc += W[h * 128 + f * 32 + o] * a[h * 32 + o];
    Wa[i] = acc;
  } else if (e < 6208) {
    int i = e - 5184;
    int kb = i >> 8, nt = (i >> 6) & 3, lane = i & 63;
    int c15 = lane & 15, quad = lane >> 4;
#pragma unroll
    for (int j = 0; j < 8; j++)
      tmp[j] = f2b(Wproj[(kb * 32 + quad * 8 + j) * 64 + nt * 16 + c15]);
    *(short8*)(fragP + i * 8) = *(short8*)tmp;
  } else if (e < 7744) {
    int i = e - 6208;
    int d = (i >= 768), r = i - d * 768;
    int kb = r / 384, nt = (r >> 6) % 6, lane = r & 63;
    int c15 = lane & 15, quad = lane >> 4;
    const float* W = d ? Wih_b : Wih_f;
#pragma unroll
    for (int j = 0; j < 8; j++)
      tmp[j] = f2b(W[(kb * 32 + quad * 8 + j) * 96 + nt * 16 + c15]);
    *(short8*)(fragIH + i * 8) = *(short8*)tmp;
  } else if (e < 9280) {
    int r = e - 7744;
    int kb = r >> 8, nt = (r >> 6) & 3, lane = r & 63;
    int c15 = lane & 15, quad = lane >> 4;
#pragma unroll
    for (int j = 0; j < 8; j++)
      tmp[j] = f2b(Wout[(kb * 32 + quad * 8 + j) * 64 + nt * 16 + c15]);
    *(short8*)(fragO + r * 8) = *(short8*)tmp;
  } else if (e < 10048) {
    int i = e - 9280;
    int d = i / 384, r = i - d * 384;
    int nt = r >> 6, lane = r & 63;
    int c15 = lane & 15, quad = lane >> 4;
    const float* W = d ? Whh_b : Whh_f;
#pragma unroll
    for (int j = 0; j < 8; j++)
      tmp[j] = f2b(W[(quad * 8 + j) * 96 + nt * 16 + c15]);
    *(short8*)(fragHH + i * 8) = *(short8*)tmp;
  }
}

// ---------------------------------------------------------------------------
// Kernel 1: GAT + fuse — PERSISTENT, weights in REGISTERS (r2 body), now at
// its natural occupancy: 1536 blocks = 6/CU (LDS 6x22.5=135KB, VGPR cap
// 512/6=85 >= the 84 the compiler chose under r2). Weights load ONCE per
// block -> no per-iteration L2 traffic -> no r3-style thrash.
// ---------------------------------------------------------------------------
__global__ __launch_bounds__(256, 6) void gat_fuse_kernel(
    const float* __restrict__ self_f, const float* __restrict__ nbr_f,
    const float* __restrict__ Wa,
    const unsigned short* __restrict__ fragWB,
    const unsigned short* __restrict__ fragB,
    const float* __restrict__ b_fuse,
    unsigned short* __restrict__ embb,
    float* __restrict__ out,
    int npairs)
{
  const int tid = threadIdx.x;
  const int w = tid >> 6, lane = tid & 63, c15 = lane & 15, quad = lane >> 4;

  __shared__ __align__(16) float sxf[2][12][4];
  __shared__ __align__(16) float sWa[64];
  __shared__ float sed[2][2][4][12];
  __shared__ __align__(16) unsigned short sA[2][2][16][24];
  __shared__ __align__(16) unsigned short scatb[2][16][268];
  __shared__ __align__(16) float sbias[128];

  // ---- one-time init ----
  if (tid < 32) ((f32x4*)sbias)[tid] = ((const f32x4*)b_fuse)[tid];
  else if (tid < 48) ((f32x4*)sWa)[tid - 32] = ((const f32x4*)Wa)[tid - 32];
  if (tid >= 128) {           // zero sA pad rows 12-15 (never rewritten)
    int t = tid - 128;
    int g = t >> 6, s = (t >> 5) & 1, i = 12 + ((t >> 3) & 3), cp = t & 7;
    *(unsigned int*)&sA[g][s][i][cp * 2] = 0u;
  }

  // ---- weight registers (persist across all iterations; loaded ONCE) ----
  const int g_q = w & 1, s_q = w >> 1;
  short8 wb3[8];                 // phase-3: fragWB slice for stream s_q
#pragma unroll
  for (int t = 0; t < 8; t++)
    wb3[t] = *(const short8*)(fragWB + ((s_q * 8 + t) * 64 + lane) * 8);
  short8 wb4[8][2];              // phase-4: fragB for N-tiles {2w, 2w+1}
#pragma unroll
  for (int kb = 0; kb < 8; kb++)
#pragma unroll
    for (int tt = 0; tt < 2; tt++)
      wb4[kb][tt] = *(const short8*)(fragB + ((kb * 8 + 2 * w + tt) * 64 + lane) * 8);

  const int chunk = (npairs + gridDim.x - 1) / gridDim.x;
  const int start = blockIdx.x * chunk;
  const int end   = min(npairs, start + chunk);
  if (start >= end) return;

  // preload x for first iteration (24 lanes x f32x4 = 2 nodes x 48 floats)
  f32x4 xr = {0.f, 0.f, 0.f, 0.f};
  int xnd = 0, xq = 0;
  if (tid < 24) {
    xnd = (tid >= 12); xq = tid - xnd * 12;
    int nn = start * 2 + xnd, b = nn / 5, slot = nn - b * 5;
    const float* src = slot ? (nbr_f + (b * 4 + slot - 1) * 48)
                            : (self_f + b * 48);
    xr = *(const f32x4*)(src + xq * 4);
  }

  for (int it = start; it < end; ++it) {
    const int n0 = it * 2;
    if (tid < 24) ((f32x4*)&sxf[xnd][0][0])[xq] = xr;
    __syncthreads();                           // barrier A (sxf ready; scatb free)
    if (tid < 24 && it + 1 < end) {            // prefetch next pair's x
      int nn = (it + 1) * 2 + xnd, b = nn / 5, slot = nn - b * 5;
      const float* src = slot ? (nbr_f + (b * 4 + slot - 1) * 48)
                              : (self_f + b * 48);
      xr = *(const f32x4*)(src + xq * 4);
    }

    // ---- phases 1+2 (wave-local softmax): wave w -> (g_q, s_q), lanes 0-47 ----
    if (lane < 48) {
      int h = lane / 12, i = lane - h * 12;
      f32x4 xv  = *(const f32x4*)&sxf[g_q][i][0];
      f32x4 was = *(const f32x4*)&sWa[s_q * 32 + h * 4];
      f32x4 wad = *(const f32x4*)&sWa[s_q * 32 + 16 + h * 4];
      float es = xv[0]*was[0] + xv[1]*was[1] + xv[2]*was[2] + xv[3]*was[3];
      float ed = xv[0]*wad[0] + xv[1]*wad[1] + xv[2]*wad[2] + xv[3]*wad[3];
      sed[g_q][s_q][h][i] = ed;
      int blk3 = (i / 3) * 3;
      float xa0 = 0.f, xa1 = 0.f, xa2 = 0.f, xa3 = 0.f, sum = 0.f;
      if (s_q == 0) {
#pragma unroll
        for (int jj = 0; jj < 3; jj++) {
          int j = blk3 + jj;
          float e = es + sed[g_q][0][h][j];
          e = e > 0.f ? e : 0.2f * e;
          float p = __expf(e);
          sum += p;
          f32x4 xj = *(const f32x4*)&sxf[g_q][j][0];
          xa0 += p * xj[0]; xa1 += p * xj[1];
          xa2 += p * xj[2]; xa3 += p * xj[3];
        }
      } else {
#pragma unroll
        for (int jj = 0; jj < 9; jj++) {
          int j = jj < blk3 ? jj : jj + 3;
          float e = es + sed[g_q][1][h][j];
          e = e > 0.f ? e : 0.2f * e;
          float p = __expf(e);
          sum += p;
          f32x4 xj = *(const f32x4*)&sxf[g_q][j][0];
          xa0 += p * xj[0]; xa1 += p * xj[1];
          xa2 += p * xj[2]; xa3 += p * xj[3];
        }
      }
      float inv = 1.f / sum;
      uint2 pk = make_uint2(pkbf(xa0 * inv, xa1 * inv),
                            pkbf(xa2 * inv, xa3 * inv));
      *(uint2*)&sA[g_q][s_q][i][h * 4] = pk;
    }

    // ---- phase 3 (operand-swapped D^T; weights from registers) ----
    {
      const short8 z8 = {0,0,0,0,0,0,0,0};
      short8 xb = z8;
      if (quad < 2) xb = *(const short8*)&sA[g_q][s_q][c15][quad * 8];
#pragma unroll
      for (int tile = 0; tile < 8; tile++) {
        f32x4 c = {0.f, 0.f, 0.f, 0.f};
        c = __builtin_amdgcn_mfma_f32_16x16x32_bf16(wb3[tile], xb, c, 0, 0, 0);
        uint2 pk = make_uint2(pkbf(eluf(c[0]), eluf(c[1])),
                              pkbf(eluf(c[2]), eluf(c[3])));
        *(uint2*)&scatb[g_q][c15][s_q * 128 + tile * 16 + (quad << 2)] = pk;
      }
    }
    __syncthreads();                           // barrier B (scatb ready)

    // ---- phase 4: fuse GEMM (weights from registers) ----
    {
      f32x4 acc[2][2];
#pragma unroll
      for (int nd = 0; nd < 2; nd++)
#pragma unroll
        for (int tt = 0; tt < 2; tt++) acc[nd][tt] = (f32x4){0.f,0.f,0.f,0.f};
#pragma unroll
      for (int kb = 0; kb < 8; kb++) {
        short8 a0 = *(const short8*)&scatb[0][c15][kb * 32 + (quad << 3)];
        short8 a1 = *(const short8*)&scatb[1][c15][kb * 32 + (quad << 3)];
#pragma unroll
        for (int tt = 0; tt < 2; tt++) {
          acc[0][tt] = __builtin_amdgcn_mfma_f32_16x16x32_bf16(a0, wb4[kb][tt], acc[0][tt], 0, 0, 0);
          acc[1][tt] = __builtin_amdgcn_mfma_f32_16x16x32_bf16(a1, wb4[kb][tt], acc[1][tt], 0, 0, 0);
        }
      }
      float tot[2][2];
#pragma unroll
      for (int nd = 0; nd < 2; nd++) {
#pragma unroll
        for (int tt = 0; tt < 2; tt++) {
          float p = 0.f;
          if (quad < 3) {
            float bcol = sbias[w * 32 + tt * 16 + c15];
#pragma unroll
            for (int r = 0; r < 4; r++) p += eluf(acc[nd][tt][r] + bcol);
          }
          p += __shfl_xor(p, 16);
          p += __shfl_xor(p, 32);
          tot[nd][tt] = p;
        }
      }
      int ndw = quad >> 1, ttw = quad & 1;
      float val = (ndw ? (ttw ? tot[1][1] : tot[1][0])
                       : (ttw ? tot[0][1] : tot[0][0])) * (1.f / 12.f);
      int node = n0 + ndw;
      int col  = w * 32 + ttw * 16 + c15;
      embb[node * 128 + col] = f2b(val);
      int bq = node / 5;
      if (node == bq * 5) out[bq * 192 + col] = val; // exact f32 passthrough
    }
  }
}

// ---------------------------------------------------------------------------
// Kernel 2: head — unchanged from round 2.
// ---------------------------------------------------------------------------
__global__ __launch_bounds__(256) void head_kernel(
    const unsigned short* __restrict__ embb,
    const float* __restrict__ maskp, const float* __restrict__ dirsp,
    const float* __restrict__ W_proj, const float* __restrict__ b_proj,
    const unsigned short* __restrict__ fragP,
    const unsigned short* __restrict__ fragIH,
    const unsigned short* __restrict__ fragHH,
    const float* __restrict__ bih_f, const float* __restrict__ bhh_f,
    const float* __restrict__ bih_b, const float* __restrict__ bhh_b,
    const unsigned short* __restrict__ fragO,
    const float* __restrict__ b_out,
    float* __restrict__ out)
{
  const int b8 = blockIdx.x * 8;
  const int tid = threadIdx.x;
  const int w = tid >> 6, lane = tid & 63, c15 = lane & 15, quad = lane >> 4;

  __shared__ __align__(16) unsigned short sX[32][72];
  __shared__ __align__(16) unsigned short sgi[2][32][96];
  __shared__ float sH[2][8][32];
  __shared__ __align__(16) unsigned short sHb[2][16][32];
  __shared__ __align__(16) float sgh[2][8][96];
  __shared__ __align__(16) unsigned short sCat[16][200];
  __shared__ __align__(16) float sPB[128];
  __shared__ __align__(16) float sBI[2][96], sBH[2][96];
  __shared__ __align__(16) float sBO[64];

  if (tid < 64) { sPB[tid] = b_proj[tid]; sPB[64 + tid] = W_proj[128 * 64 + tid]; sBO[tid] = b_out[tid]; }
  if (tid < 96) { sBI[0][tid] = bih_f[tid]; sBI[1][tid] = bih_b[tid];
                  sBH[0][tid] = bhh_f[tid]; sBH[1][tid] = bhh_b[tid]; }
  {
    unsigned int* hb = (unsigned int*)sHb;     // 512 dwords
    hb[tid] = 0u; hb[tid + 256] = 0u;
    float* hz = (float*)sH;
    for (int i = tid; i < 512; i += 256) hz[i] = 0.f;
  }
  __syncthreads();                             // B1

  // ---- proj via MFMA (swapped) ----
  {
    const int mt  = w >> 1;
    const int nt0 = (w & 1) * 2;
    const int sloc = mt * 4 + (c15 >> 2);
    const int nbr  = c15 & 3;
    const unsigned short* brow = embb + (((b8 + sloc) * 5) + 1 + nbr) * 128;
    short8 xb[4];
#pragma unroll
    for (int kb = 0; kb < 4; kb++)
      xb[kb] = *(const short8*)(brow + kb * 32 + quad * 8);
    f32x4 acc0 = {0.f,0.f,0.f,0.f}, acc1 = acc0;
#pragma unroll
    for (int kb = 0; kb < 4; kb++) {
      short8 a0 = *(const short8*)(fragP + ((kb * 4 + nt0    ) * 64 + lane) * 8);
      short8 a1 = *(const short8*)(fragP + ((kb * 4 + nt0 + 1) * 64 + lane) * 8);
      acc0 = __builtin_amdgcn_mfma_f32_16x16x32_bf16(a0, xb[kb], acc0, 0, 0, 0);
      acc1 = __builtin_amdgcn_mfma_f32_16x16x32_bf16(a1, xb[kb], acc1, 0, 0, 0);
    }
    const float dirv  = dirsp[(b8 + sloc) * 4 + nbr];
    const float maskv = maskp[(b8 + sloc) * 4 + nbr];
#pragma unroll
    for (int tt = 0; tt < 2; tt++) {
      f32x4 c = tt ? acc1 : acc0;
      int colb = (nt0 + tt) * 16 + (quad << 2);
      f32x4 wp = *(const f32x4*)&sPB[64 + colb];
      f32x4 pb = *(const f32x4*)&sPB[colb];
      float v0 = fmaxf(c[0] + dirv * wp[0] + pb[0], 0.f) * maskv;
      float v1 = fmaxf(c[1] + dirv * wp[1] + pb[1], 0.f) * maskv;
      float v2 = fmaxf(c[2] + dirv * wp[2] + pb[2], 0.f) * maskv;
      float v3 = fmaxf(c[3] + dirv * wp[3] + pb[3], 0.f) * maskv;
      uint2 pk = make_uint2(pkbf(v0, v1), pkbf(v2, v3));
      *(uint2*)&sX[mt * 16 + c15][colb] = pk;
    }
  }
  __syncthreads();                             // B2

  // ---- gi via MFMA + sCat self-emb staging ----
  {
    const int mt  = w >> 1;
    const int ntb = (w & 1) * 3;
    short8 xb0 = *(const short8*)&sX[mt * 16 + c15][quad * 8];
    short8 xb1 = *(const short8*)&sX[mt * 16 + c15][32 + quad * 8];
#pragma unroll
    for (int d = 0; d < 2; d++) {
#pragma unroll
      for (int t2 = 0; t2 < 3; t2++) {
        int nt = ntb + t2;
        f32x4 acc = {0.f,0.f,0.f,0.f};
        short8 a0 = *(const short8*)(fragIH + ((d * 12 +     nt) * 64 + lane) * 8);
        short8 a1 = *(const short8*)(fragIH + ((d * 12 + 6 + nt) * 64 + lane) * 8);
        acc = __builtin_amdgcn_mfma_f32_16x16x32_bf16(a0, xb0, acc, 0, 0, 0);
        acc = __builtin_amdgcn_mfma_f32_16x16x32_bf16(a1, xb1, acc, 0, 0, 0);
        f32x4 bi = *(const f32x4*)&sBI[d][nt * 16 + (quad << 2)];
        uint2 pk = make_uint2(pkbf(acc[0] + bi[0], acc[1] + bi[1]),
                              pkbf(acc[2] + bi[2], acc[3] + bi[3]));
        *(uint2*)&sgi[d][mt * 16 + c15][nt * 16 + (quad << 2)] = pk;
      }
    }
    if (tid >= 128) {                          // stage self_emb -> sCat[:,0:128]
      int t = tid - 128;                       // 0..127
      int s = t >> 4, c8 = (t & 15) * 8;
      short8 v = *(const short8*)(embb + (b8 + s) * 5 * 128 + c8);
      *(short8*)&sCat[s][c8] = v;
    }
  }
  __syncthreads();                             // B3

  // ---- GRU: 4 waves = (dir d = w>>1) x (sample-half q = w&1), 4 samples each.
  {
    const int d = w >> 1;
    const int q = w & 1;
    const int u = lane & 31, sp = lane >> 5;
    for (int step = 0; step < 4; step++) {
      short8 hb = *(const short8*)&sHb[d][c15][quad * 8];
#pragma unroll
      for (int nt = 0; nt < 6; nt++) {
        short8 aw = *(const short8*)(fragHH + ((d * 6 + nt) * 64 + lane) * 8);
        f32x4 c = {0.f,0.f,0.f,0.f};
        c = __builtin_amdgcn_mfma_f32_16x16x32_bf16(aw, hb, c, 0, 0, 0);
        if ((c15 >> 2) == q)                   // own sample rows only
          *(f32x4*)&sgh[d][c15][nt * 16 + (quad << 2)] = c;
      }
      const int k = d ? (3 - step) : step;
#pragma unroll
      for (int si = 0; si < 2; si++) {
        int s = q * 4 + sp + si * 2;
        int row = s * 4 + k;
        float ghr = sgh[d][s][u]      + sBH[d][u];
        float ghz = sgh[d][s][32 + u] + sBH[d][32 + u];
        float ghn = sgh[d][s][64 + u] + sBH[d][64 + u];
        float r = sigm(b2f_u(sgi[d][row][u]) + ghr);
        float z = sigm(b2f_u(sgi[d][row][32 + u]) + ghz);
        float n = tanhfast(b2f_u(sgi[d][row][64 + u]) + r * ghn);
        float h = (1.f - z) * n + z * sH[d][s][u];
        sH[d][s][u] = h;
        sHb[d][s][u] = f2b(h);
        if (step == 3) sCat[s][128 + d * 32 + u] = f2b(h);
      }
    }
  }
  __syncthreads();                             // B4

  // ---- out head via MFMA (swapped) ----
  {
    const int nt = w;
    f32x4 acc = {0.f,0.f,0.f,0.f};
#pragma unroll
    for (int kb = 0; kb < 6; kb++) {
      short8 bb = *(const short8*)&sCat[c15][kb * 32 + quad * 8];
      short8 aw = *(const short8*)(fragO + ((kb * 4 + nt) * 64 + lane) * 8);
      acc = __builtin_amdgcn_mfma_f32_16x16x32_bf16(aw, bb, acc, 0, 0, 0);
    }
    if (c15 < 8) {                             // D[out-col][sample]
      f32x4 bo = *(const f32x4*)&sBO[nt * 16 + (quad << 2)];
      f32x4 v;
      v[0] = fmaxf(acc[0] + bo[0], 0.f);
      v[1] = fmaxf(acc[1] + bo[1], 0.f);
      v[2] = fmaxf(acc[2] + bo[2], 0.f);
      v[3] = fmaxf(acc[3] + bo[3], 0.f);
      *(f32x4*)(out + (b8 + c15) * 192 + 128 + nt * 16 + (quad << 2)) = v;
    }
  }
}

// ---------------------------------------------------------------------------
extern "C" void kernel_launch(void* const* d_in, const int* in_sizes, int n_in,
                              void* d_out, int out_size, void* d_ws, size_t ws_size,
                              hipStream_t stream) {
  const float* self_f  = (const float*)d_in[0];
  const float* nbr_f   = (const float*)d_in[1];
  const float* maskp   = (const float*)d_in[2];
  const float* dirsp   = (const float*)d_in[3];
  const float* W_coop  = (const float*)d_in[4];
  const float* as_coop = (const float*)d_in[5];
  const float* ad_coop = (const float*)d_in[6];
  const float* W_conf  = (const float*)d_in[7];
  const float* as_conf = (const float*)d_in[8];
  const float* ad_conf = (const float*)d_in[9];
  const float* W_fuse  = (const float*)d_in[10];
  const float* b_fuse  = (const float*)d_in[11];
  const float* W_proj  = (const float*)d_in[12];
  const float* b_proj  = (const float*)d_in[13];
  const float* Wih_f   = (const float*)d_in[14];
  const float* Whh_f   = (const float*)d_in[15];
  const float* bih_f   = (const float*)d_in[16];
  const float* bhh_f   = (const float*)d_in[17];
  const float* Wih_b   = (const float*)d_in[18];
  const float* Whh_b   = (const float*)d_in[19];
  const float* bih_b   = (const float*)d_in[20];
  const float* bhh_b   = (const float*)d_in[21];
  const float* W_out   = (const float*)d_in[22];
  const float* b_out   = (const float*)d_in[23];

  const int B = in_sizes[0] / 48;   // 8192
  char* ws = (char*)d_ws;
  unsigned short* fragB  = (unsigned short*)(ws);            // 65536 B
  unsigned short* fragWB = (unsigned short*)(ws + 65536);    // 16384 B
  float*          Wa     = (float*)(ws + 81920);             // 256 B
  unsigned short* fragP  = (unsigned short*)(ws + 82176);    // 16384 B
  unsigned short* fragIH = (unsigned short*)(ws + 98560);    // 24576 B
  unsigned short* fragO  = (unsigned short*)(ws + 123136);   // 24576 B
  unsigned short* fragHH = (unsigned short*)(ws + 147712);   // 12288 B
  unsigned short* embb   = (unsigned short*)(ws + 160000);   // B*5*128*2

  prepack_kernel<<<40, 256, 0, stream>>>(
      W_fuse, W_coop, W_conf, as_coop, ad_coop, as_conf, ad_conf,
      W_proj, Wih_f, Wih_b, W_out, Whh_f, Whh_b,
      fragB, fragWB, Wa, fragP, fragIH, fragO, fragHH);

  const int npairs = B * 5 / 2;   // 20480
  gat_fuse_kernel<<<1536, 256, 0, stream>>>(
      self_f, nbr_f, Wa, fragWB, fragB, b_fuse, embb, (float*)d_out, npairs);

  head_kernel<<<B / 8, 256, 0, stream>>>(
      embb, maskp, dirsp, W_proj, b_proj, fragP, fragIH, fragHH,
      bih_f, bhh_f, bih_b, bhh_b,
      fragO, b_out, (float*)d_out);
}

// Round 5
// 242.412 us; speedup vs baseline: 1.6591x; 1.6057x over previous
//
#include <hip/hip_runtime.h>
#include <hip/hip_bf16.h>
#include <math.h>

typedef short short8 __attribute__((ext_vector_type(8)));
typedef float f32x4  __attribute__((ext_vector_type(4)));

__device__ __forceinline__ unsigned short f2b(float f) {
  union { float f; unsigned int u; } x; x.f = f;
  return (unsigned short)((x.u + 0x7FFFu + ((x.u >> 16) & 1u)) >> 16);
}
__device__ __forceinline__ float b2f_u(unsigned short u) {
  union { unsigned int u; float f; } x; x.u = ((unsigned int)u) << 16;
  return x.f;
}
// packed f32x2 -> bf16x2 (v_cvt_pk_bf16_f32, RTNE)
__device__ __forceinline__ unsigned int pkbf(float a, float b) {
  union { __hip_bfloat162 h; unsigned int u; } c;
  c.h = __float22bfloat162_rn(make_float2(a, b));
  return c.u;
}
__device__ __forceinline__ float sigm(float x) {
  return __builtin_amdgcn_rcpf(1.f + __expf(-x));
}
__device__ __forceinline__ float tanhfast(float x) {
  float ax = fabsf(x);
  float em = __expf(-2.f * ax);
  float t  = (1.f - em) * __builtin_amdgcn_rcpf(1.f + em);
  return copysignf(t, x);
}
__device__ __forceinline__ float eluf(float v) {
  return v > 0.f ? v : (__expf(v) - 1.f);
}

// ---------------------------------------------------------------------------
// Prepack (unchanged).
// ---------------------------------------------------------------------------
__global__ __launch_bounds__(256) void prepack_kernel(
    const float* __restrict__ Wf,
    const float* __restrict__ Wc, const float* __restrict__ Wn,
    const float* __restrict__ as_c, const float* __restrict__ ad_c,
    const float* __restrict__ as_n, const float* __restrict__ ad_n,
    const float* __restrict__ Wproj,
    const float* __restrict__ Wih_f, const float* __restrict__ Wih_b,
    const float* __restrict__ Wout,
    const float* __restrict__ Whh_f, const float* __restrict__ Whh_b,
    unsigned short* __restrict__ fragB,
    unsigned short* __restrict__ fragWB,
    float* __restrict__ Wa,
    unsigned short* __restrict__ fragP,
    unsigned short* __restrict__ fragIH,
    unsigned short* __restrict__ fragO,
    unsigned short* __restrict__ fragHH)
{
  int e = blockIdx.x * 256 + threadIdx.x;
  unsigned short tmp[8];
  if (e < 4096) {
    int kb = e >> 9, tile = (e >> 6) & 7, lane = e & 63;
    int n = tile * 16 + (lane & 15);
    int kbase = kb * 32 + (lane >> 4) * 8;
#pragma unroll
    for (int j = 0; j < 8; j++) tmp[j] = f2b(Wf[(kbase + j) * 128 + n]);
    *(short8*)(fragB + e * 8) = *(short8*)tmp;
  } else if (e < 5120) {
    int i = e - 4096;
    int s = i >> 9, tile = (i >> 6) & 7, lane = i & 63;
    int c15 = lane & 15, quad = lane >> 4;
    int n = tile * 16 + c15;
    int h = n >> 5, o = n & 31;
    const float* W = s ? Wn : Wc;
#pragma unroll
    for (int j = 0; j < 8; j++) {
      int k = quad * 8 + j;
      tmp[j] = ((k >> 2) == h) ? f2b(W[h * 128 + (k & 3) * 32 + o])
                               : (unsigned short)0;
    }
    *(short8*)(fragWB + i * 8) = *(short8*)tmp;
  } else if (e < 5184) {
    int i = e - 5120;
    int s = i >> 5, d = (i >> 4) & 1, h = (i >> 2) & 3, f = i & 3;
    const float* W = s ? Wn : Wc;
    const float* a = s ? (d ? ad_n : as_n) : (d ? ad_c : as_c);
    float acc = 0.f;
#pragma unroll
    for (int o = 0; o < 32; o++) acc += W[h * 128 + f * 32 + o] * a[h * 32 + o];
    Wa[i] = acc;
  } else if (e < 6208) {
    int i = e - 5184;
    int kb = i >> 8, nt = (i >> 6) & 3, lane = i & 63;
    int c15 = lane & 15, quad = lane >> 4;
#pragma unroll
    for (int j = 0; j < 8; j++)
      tmp[j] = f2b(Wproj[(kb * 32 + quad * 8 + j) * 64 + nt * 16 + c15]);
    *(short8*)(fragP + i * 8) = *(short8*)tmp;
  } else if (e < 7744) {
    int i = e - 6208;
    int d = (i >= 768), r = i - d * 768;
    int kb = r / 384, nt = (r >> 6) % 6, lane = r & 63;
    int c15 = lane & 15, quad = lane >> 4;
    const float* W = d ? Wih_b : Wih_f;
#pragma unroll
    for (int j = 0; j < 8; j++)
      tmp[j] = f2b(W[(kb * 32 + quad * 8 + j) * 96 + nt * 16 + c15]);
    *(short8*)(fragIH + i * 8) = *(short8*)tmp;
  } else if (e < 9280) {
    int r = e - 7744;
    int kb = r >> 8, nt = (r >> 6) & 3, lane = r & 63;
    int c15 = lane & 15, quad = lane >> 4;
#pragma unroll
    for (int j = 0; j < 8; j++)
      tmp[j] = f2b(Wout[(kb * 32 + quad * 8 + j) * 64 + nt * 16 + c15]);
    *(short8*)(fragO + r * 8) = *(short8*)tmp;
  } else if (e < 10048) {
    int i = e - 9280;
    int d = i / 384, r = i - d * 384;
    int nt = r >> 6, lane = r & 63;
    int c15 = lane & 15, quad = lane >> 4;
    const float* W = d ? Whh_b : Whh_f;
#pragma unroll
    for (int j = 0; j < 8; j++)
      tmp[j] = f2b(W[(quad * 8 + j) * 96 + nt * 16 + c15]);
    *(short8*)(fragHH + i * 8) = *(short8*)tmp;
  }
}

// ---------------------------------------------------------------------------
// Kernel 1: GAT + fuse — 4 pairs per block, NO launch_bounds min-waves (the
// r3/r4 scratch-thrash poison), NO weight-register hoisting (the r2 occupancy
// poison). Weights load per-use from L2 via loop-invariant base pointers
// (r0/r1-proven: ~2 GB of requests, 99.7% L2 hit). x prefetched one pair
// ahead in registers. Expected codegen: VGPR ~40-56, zero scratch,
// 7 blocks/CU (LDS-capped).
// ---------------------------------------------------------------------------
__global__ __launch_bounds__(256) void gat_fuse_kernel(
    const float* __restrict__ self_f, const float* __restrict__ nbr_f,
    const float* __restrict__ Wa,
    const unsigned short* __restrict__ fragWB,
    const unsigned short* __restrict__ fragB,
    const float* __restrict__ b_fuse,
    unsigned short* __restrict__ embb,
    float* __restrict__ out,
    int npairs)
{
  const int tid = threadIdx.x;
  const int w = tid >> 6, lane = tid & 63, c15 = lane & 15, quad = lane >> 4;

  __shared__ __align__(16) float sxf[2][12][4];
  __shared__ __align__(16) float sWa[64];
  __shared__ float sed[2][2][4][12];
  __shared__ __align__(16) unsigned short sA[2][2][16][24];
  __shared__ __align__(16) unsigned short scatb[2][16][268];
  __shared__ __align__(16) float sbias[128];

  // ---- one-time init ----
  if (tid < 32) ((f32x4*)sbias)[tid] = ((const f32x4*)b_fuse)[tid];
  else if (tid < 48) ((f32x4*)sWa)[tid - 32] = ((const f32x4*)Wa)[tid - 32];
  if (tid >= 128) {           // zero sA pad rows 12-15 (never rewritten)
    int t = tid - 128;
    int g = t >> 6, s = (t >> 5) & 1, i = 12 + ((t >> 3) & 3), cp = t & 7;
    *(unsigned int*)&sA[g][s][i][cp * 2] = 0u;
  }

  const int g_q = w & 1, s_q = w >> 1;
  // loop-invariant weight base pointers; offsets in-loop are constants.
  const unsigned short* __restrict__ pwb3 = fragWB + (s_q * 8 * 64 + lane) * 8;
  const unsigned short* __restrict__ pwb4 = fragB + (2 * w * 64 + lane) * 8;

  const int start = blockIdx.x * 4;
  const int end   = min(npairs, start + 4);

  // preload x for first iteration (24 lanes x f32x4 = 2 nodes x 48 floats)
  f32x4 xr = {0.f, 0.f, 0.f, 0.f};
  int xnd = 0, xq = 0;
  if (tid < 24) {
    xnd = (tid >= 12); xq = tid - xnd * 12;
    int nn = start * 2 + xnd, b = nn / 5, slot = nn - b * 5;
    const float* src = slot ? (nbr_f + (b * 4 + slot - 1) * 48)
                            : (self_f + b * 48);
    xr = *(const f32x4*)(src + xq * 4);
  }

  for (int it = start; it < end; ++it) {
    const int n0 = it * 2;
    if (tid < 24) ((f32x4*)&sxf[xnd][0][0])[xq] = xr;
    __syncthreads();                           // barrier A (sxf ready; scatb free)
    if (tid < 24 && it + 1 < end) {            // prefetch next pair's x
      int nn = (it + 1) * 2 + xnd, b = nn / 5, slot = nn - b * 5;
      const float* src = slot ? (nbr_f + (b * 4 + slot - 1) * 48)
                              : (self_f + b * 48);
      xr = *(const f32x4*)(src + xq * 4);
    }

    // ---- phases 1+2 (wave-local softmax): wave w -> (g_q, s_q), lanes 0-47 ----
    if (lane < 48) {
      int h = lane / 12, i = lane - h * 12;
      f32x4 xv  = *(const f32x4*)&sxf[g_q][i][0];
      f32x4 was = *(const f32x4*)&sWa[s_q * 32 + h * 4];
      f32x4 wad = *(const f32x4*)&sWa[s_q * 32 + 16 + h * 4];
      float es = xv[0]*was[0] + xv[1]*was[1] + xv[2]*was[2] + xv[3]*was[3];
      float ed = xv[0]*wad[0] + xv[1]*wad[1] + xv[2]*wad[2] + xv[3]*wad[3];
      sed[g_q][s_q][h][i] = ed;
      int blk3 = (i / 3) * 3;
      float xa0 = 0.f, xa1 = 0.f, xa2 = 0.f, xa3 = 0.f, sum = 0.f;
      if (s_q == 0) {
#pragma unroll
        for (int jj = 0; jj < 3; jj++) {
          int j = blk3 + jj;
          float e = es + sed[g_q][0][h][j];
          e = e > 0.f ? e : 0.2f * e;
          float p = __expf(e);
          sum += p;
          f32x4 xj = *(const f32x4*)&sxf[g_q][j][0];
          xa0 += p * xj[0]; xa1 += p * xj[1];
          xa2 += p * xj[2]; xa3 += p * xj[3];
        }
      } else {
#pragma unroll
        for (int jj = 0; jj < 9; jj++) {
          int j = jj < blk3 ? jj : jj + 3;
          float e = es + sed[g_q][1][h][j];
          e = e > 0.f ? e : 0.2f * e;
          float p = __expf(e);
          sum += p;
          f32x4 xj = *(const f32x4*)&sxf[g_q][j][0];
          xa0 += p * xj[0]; xa1 += p * xj[1];
          xa2 += p * xj[2]; xa3 += p * xj[3];
        }
      }
      float inv = 1.f / sum;
      uint2 pk = make_uint2(pkbf(xa0 * inv, xa1 * inv),
                            pkbf(xa2 * inv, xa3 * inv));
      *(uint2*)&sA[g_q][s_q][i][h * 4] = pk;
    }

    // ---- phase 3 (operand-swapped D^T; per-use weight loads, L2-hot) ----
    {
      const short8 z8 = {0,0,0,0,0,0,0,0};
      short8 xb = z8;
      if (quad < 2) xb = *(const short8*)&sA[g_q][s_q][c15][quad * 8];
#pragma unroll
      for (int tile = 0; tile < 8; tile++) {
        short8 aw = *(const short8*)(pwb3 + tile * 512);
        f32x4 c = {0.f, 0.f, 0.f, 0.f};
        c = __builtin_amdgcn_mfma_f32_16x16x32_bf16(aw, xb, c, 0, 0, 0);
        uint2 pk = make_uint2(pkbf(eluf(c[0]), eluf(c[1])),
                              pkbf(eluf(c[2]), eluf(c[3])));
        *(uint2*)&scatb[g_q][c15][s_q * 128 + tile * 16 + (quad << 2)] = pk;
      }
    }
    __syncthreads();                           // barrier B (scatb ready)

    // ---- phase 4: fuse GEMM (per-use weight loads, L2-hot) ----
    {
      f32x4 acc[2][2];
#pragma unroll
      for (int nd = 0; nd < 2; nd++)
#pragma unroll
        for (int tt = 0; tt < 2; tt++) acc[nd][tt] = (f32x4){0.f,0.f,0.f,0.f};
#pragma unroll
      for (int kb = 0; kb < 8; kb++) {
        short8 a0 = *(const short8*)&scatb[0][c15][kb * 32 + (quad << 3)];
        short8 a1 = *(const short8*)&scatb[1][c15][kb * 32 + (quad << 3)];
#pragma unroll
        for (int tt = 0; tt < 2; tt++) {
          short8 bw = *(const short8*)(pwb4 + kb * 4096 + tt * 512);
          acc[0][tt] = __builtin_amdgcn_mfma_f32_16x16x32_bf16(a0, bw, acc[0][tt], 0, 0, 0);
          acc[1][tt] = __builtin_amdgcn_mfma_f32_16x16x32_bf16(a1, bw, acc[1][tt], 0, 0, 0);
        }
      }
      float tot[2][2];
#pragma unroll
      for (int nd = 0; nd < 2; nd++) {
#pragma unroll
        for (int tt = 0; tt < 2; tt++) {
          float p = 0.f;
          if (quad < 3) {
            float bcol = sbias[w * 32 + tt * 16 + c15];
#pragma unroll
            for (int r = 0; r < 4; r++) p += eluf(acc[nd][tt][r] + bcol);
          }
          p += __shfl_xor(p, 16);
          p += __shfl_xor(p, 32);
          tot[nd][tt] = p;
        }
      }
      int ndw = quad >> 1, ttw = quad & 1;
      float val = (ndw ? (ttw ? tot[1][1] : tot[1][0])
                       : (ttw ? tot[0][1] : tot[0][0])) * (1.f / 12.f);
      int node = n0 + ndw;
      int col  = w * 32 + ttw * 16 + c15;
      embb[node * 128 + col] = f2b(val);
      int bq = node / 5;
      if (node == bq * 5) out[bq * 192 + col] = val; // exact f32 passthrough
    }
  }
}

// ---------------------------------------------------------------------------
// Kernel 2: head — unchanged from round 2.
// ---------------------------------------------------------------------------
__global__ __launch_bounds__(256) void head_kernel(
    const unsigned short* __restrict__ embb,
    const float* __restrict__ maskp, const float* __restrict__ dirsp,
    const float* __restrict__ W_proj, const float* __restrict__ b_proj,
    const unsigned short* __restrict__ fragP,
    const unsigned short* __restrict__ fragIH,
    const unsigned short* __restrict__ fragHH,
    const float* __restrict__ bih_f, const float* __restrict__ bhh_f,
    const float* __restrict__ bih_b, const float* __restrict__ bhh_b,
    const unsigned short* __restrict__ fragO,
    const float* __restrict__ b_out,
    float* __restrict__ out)
{
  const int b8 = blockIdx.x * 8;
  const int tid = threadIdx.x;
  const int w = tid >> 6, lane = tid & 63, c15 = lane & 15, quad = lane >> 4;

  __shared__ __align__(16) unsigned short sX[32][72];
  __shared__ __align__(16) unsigned short sgi[2][32][96];
  __shared__ float sH[2][8][32];
  __shared__ __align__(16) unsigned short sHb[2][16][32];
  __shared__ __align__(16) float sgh[2][8][96];
  __shared__ __align__(16) unsigned short sCat[16][200];
  __shared__ __align__(16) float sPB[128];
  __shared__ __align__(16) float sBI[2][96], sBH[2][96];
  __shared__ __align__(16) float sBO[64];

  if (tid < 64) { sPB[tid] = b_proj[tid]; sPB[64 + tid] = W_proj[128 * 64 + tid]; sBO[tid] = b_out[tid]; }
  if (tid < 96) { sBI[0][tid] = bih_f[tid]; sBI[1][tid] = bih_b[tid];
                  sBH[0][tid] = bhh_f[tid]; sBH[1][tid] = bhh_b[tid]; }
  {
    unsigned int* hb = (unsigned int*)sHb;     // 512 dwords
    hb[tid] = 0u; hb[tid + 256] = 0u;
    float* hz = (float*)sH;
    for (int i = tid; i < 512; i += 256) hz[i] = 0.f;
  }
  __syncthreads();                             // B1

  // ---- proj via MFMA (swapped) ----
  {
    const int mt  = w >> 1;
    const int nt0 = (w & 1) * 2;
    const int sloc = mt * 4 + (c15 >> 2);
    const int nbr  = c15 & 3;
    const unsigned short* brow = embb + (((b8 + sloc) * 5) + 1 + nbr) * 128;
    short8 xb[4];
#pragma unroll
    for (int kb = 0; kb < 4; kb++)
      xb[kb] = *(const short8*)(brow + kb * 32 + quad * 8);
    f32x4 acc0 = {0.f,0.f,0.f,0.f}, acc1 = acc0;
#pragma unroll
    for (int kb = 0; kb < 4; kb++) {
      short8 a0 = *(const short8*)(fragP + ((kb * 4 + nt0    ) * 64 + lane) * 8);
      short8 a1 = *(const short8*)(fragP + ((kb * 4 + nt0 + 1) * 64 + lane) * 8);
      acc0 = __builtin_amdgcn_mfma_f32_16x16x32_bf16(a0, xb[kb], acc0, 0, 0, 0);
      acc1 = __builtin_amdgcn_mfma_f32_16x16x32_bf16(a1, xb[kb], acc1, 0, 0, 0);
    }
    const float dirv  = dirsp[(b8 + sloc) * 4 + nbr];
    const float maskv = maskp[(b8 + sloc) * 4 + nbr];
#pragma unroll
    for (int tt = 0; tt < 2; tt++) {
      f32x4 c = tt ? acc1 : acc0;
      int colb = (nt0 + tt) * 16 + (quad << 2);
      f32x4 wp = *(const f32x4*)&sPB[64 + colb];
      f32x4 pb = *(const f32x4*)&sPB[colb];
      float v0 = fmaxf(c[0] + dirv * wp[0] + pb[0], 0.f) * maskv;
      float v1 = fmaxf(c[1] + dirv * wp[1] + pb[1], 0.f) * maskv;
      float v2 = fmaxf(c[2] + dirv * wp[2] + pb[2], 0.f) * maskv;
      float v3 = fmaxf(c[3] + dirv * wp[3] + pb[3], 0.f) * maskv;
      uint2 pk = make_uint2(pkbf(v0, v1), pkbf(v2, v3));
      *(uint2*)&sX[mt * 16 + c15][colb] = pk;
    }
  }
  __syncthreads();                             // B2

  // ---- gi via MFMA + sCat self-emb staging ----
  {
    const int mt  = w >> 1;
    const int ntb = (w & 1) * 3;
    short8 xb0 = *(const short8*)&sX[mt * 16 + c15][quad * 8];
    short8 xb1 = *(const short8*)&sX[mt * 16 + c15][32 + quad * 8];
#pragma unroll
    for (int d = 0; d < 2; d++) {
#pragma unroll
      for (int t2 = 0; t2 < 3; t2++) {
        int nt = ntb + t2;
        f32x4 acc = {0.f,0.f,0.f,0.f};
        short8 a0 = *(const short8*)(fragIH + ((d * 12 +     nt) * 64 + lane) * 8);
        short8 a1 = *(const short8*)(fragIH + ((d * 12 + 6 + nt) * 64 + lane) * 8);
        acc = __builtin_amdgcn_mfma_f32_16x16x32_bf16(a0, xb0, acc, 0, 0, 0);
        acc = __builtin_amdgcn_mfma_f32_16x16x32_bf16(a1, xb1, acc, 0, 0, 0);
        f32x4 bi = *(const f32x4*)&sBI[d][nt * 16 + (quad << 2)];
        uint2 pk = make_uint2(pkbf(acc[0] + bi[0], acc[1] + bi[1]),
                              pkbf(acc[2] + bi[2], acc[3] + bi[3]));
        *(uint2*)&sgi[d][mt * 16 + c15][nt * 16 + (quad << 2)] = pk;
      }
    }
    if (tid >= 128) {                          // stage self_emb -> sCat[:,0:128]
      int t = tid - 128;                       // 0..127
      int s = t >> 4, c8 = (t & 15) * 8;
      short8 v = *(const short8*)(embb + (b8 + s) * 5 * 128 + c8);
      *(short8*)&sCat[s][c8] = v;
    }
  }
  __syncthreads();                             // B3

  // ---- GRU: 4 waves = (dir d = w>>1) x (sample-half q = w&1), 4 samples each.
  {
    const int d = w >> 1;
    const int q = w & 1;
    const int u = lane & 31, sp = lane >> 5;
    for (int step = 0; step < 4; step++) {
      short8 hb = *(const short8*)&sHb[d][c15][quad * 8];
#pragma unroll
      for (int nt = 0; nt < 6; nt++) {
        short8 aw = *(const short8*)(fragHH + ((d * 6 + nt) * 64 + lane) * 8);
        f32x4 c = {0.f,0.f,0.f,0.f};
        c = __builtin_amdgcn_mfma_f32_16x16x32_bf16(aw, hb, c, 0, 0, 0);
        if ((c15 >> 2) == q)                   // own sample rows only
          *(f32x4*)&sgh[d][c15][nt * 16 + (quad << 2)] = c;
      }
      const int k = d ? (3 - step) : step;
#pragma unroll
      for (int si = 0; si < 2; si++) {
        int s = q * 4 + sp + si * 2;
        int row = s * 4 + k;
        float ghr = sgh[d][s][u]      + sBH[d][u];
        float ghz = sgh[d][s][32 + u] + sBH[d][32 + u];
        float ghn = sgh[d][s][64 + u] + sBH[d][64 + u];
        float r = sigm(b2f_u(sgi[d][row][u]) + ghr);
        float z = sigm(b2f_u(sgi[d][row][32 + u]) + ghz);
        float n = tanhfast(b2f_u(sgi[d][row][64 + u]) + r * ghn);
        float h = (1.f - z) * n + z * sH[d][s][u];
        sH[d][s][u] = h;
        sHb[d][s][u] = f2b(h);
        if (step == 3) sCat[s][128 + d * 32 + u] = f2b(h);
      }
    }
  }
  __syncthreads();                             // B4

  // ---- out head via MFMA (swapped) ----
  {
    const int nt = w;
    f32x4 acc = {0.f,0.f,0.f,0.f};
#pragma unroll
    for (int kb = 0; kb < 6; kb++) {
      short8 bb = *(const short8*)&sCat[c15][kb * 32 + quad * 8];
      short8 aw = *(const short8*)(fragO + ((kb * 4 + nt) * 64 + lane) * 8);
      acc = __builtin_amdgcn_mfma_f32_16x16x32_bf16(aw, bb, acc, 0, 0, 0);
    }
    if (c15 < 8) {                             // D[out-col][sample]
      f32x4 bo = *(const f32x4*)&sBO[nt * 16 + (quad << 2)];
      f32x4 v;
      v[0] = fmaxf(acc[0] + bo[0], 0.f);
      v[1] = fmaxf(acc[1] + bo[1], 0.f);
      v[2] = fmaxf(acc[2] + bo[2], 0.f);
      v[3] = fmaxf(acc[3] + bo[3], 0.f);
      *(f32x4*)(out + (b8 + c15) * 192 + 128 + nt * 16 + (quad << 2)) = v;
    }
  }
}

// ---------------------------------------------------------------------------
extern "C" void kernel_launch(void* const* d_in, const int* in_sizes, int n_in,
                              void* d_out, int out_size, void* d_ws, size_t ws_size,
                              hipStream_t stream) {
  const float* self_f  = (const float*)d_in[0];
  const float* nbr_f   = (const float*)d_in[1];
  const float* maskp   = (const float*)d_in[2];
  const float* dirsp   = (const float*)d_in[3];
  const float* W_coop  = (const float*)d_in[4];
  const float* as_coop = (const float*)d_in[5];
  const float* ad_coop = (const float*)d_in[6];
  const float* W_conf  = (const float*)d_in[7];
  const float* as_conf = (const float*)d_in[8];
  const float* ad_conf = (const float*)d_in[9];
  const float* W_fuse  = (const float*)d_in[10];
  const float* b_fuse  = (const float*)d_in[11];
  const float* W_proj  = (const float*)d_in[12];
  const float* b_proj  = (const float*)d_in[13];
  const float* Wih_f   = (const float*)d_in[14];
  const float* Whh_f   = (const float*)d_in[15];
  const float* bih_f   = (const float*)d_in[16];
  const float* bhh_f   = (const float*)d_in[17];
  const float* Wih_b   = (const float*)d_in[18];
  const float* Whh_b   = (const float*)d_in[19];
  const float* bih_b   = (const float*)d_in[20];
  const float* bhh_b   = (const float*)d_in[21];
  const float* W_out   = (const float*)d_in[22];
  const float* b_out   = (const float*)d_in[23];

  const int B = in_sizes[0] / 48;   // 8192
  char* ws = (char*)d_ws;
  unsigned short* fragB  = (unsigned short*)(ws);            // 65536 B
  unsigned short* fragWB = (unsigned short*)(ws + 65536);    // 16384 B
  float*          Wa     = (float*)(ws + 81920);             // 256 B
  unsigned short* fragP  = (unsigned short*)(ws + 82176);    // 16384 B
  unsigned short* fragIH = (unsigned short*)(ws + 98560);    // 24576 B
  unsigned short* fragO  = (unsigned short*)(ws + 123136);   // 24576 B
  unsigned short* fragHH = (unsigned short*)(ws + 147712);   // 12288 B
  unsigned short* embb   = (unsigned short*)(ws + 160000);   // B*5*128*2

  prepack_kernel<<<40, 256, 0, stream>>>(
      W_fuse, W_coop, W_conf, as_coop, ad_coop, as_conf, ad_conf,
      W_proj, Wih_f, Wih_b, W_out, Whh_f, Whh_b,
      fragB, fragWB, Wa, fragP, fragIH, fragO, fragHH);

  const int npairs = B * 5 / 2;   // 20480
  gat_fuse_kernel<<<npairs / 4, 256, 0, stream>>>(
      self_f, nbr_f, Wa, fragWB, fragB, b_fuse, embb, (float*)d_out, npairs);

  head_kernel<<<B / 8, 256, 0, stream>>>(
      embb, maskp, dirsp, W_proj, b_proj, fragP, fragIH, fragHH,
      bih_f, bhh_f, bih_b, bhh_b,
      fragO, b_out, (float*)d_out);
}

// Round 6
// 224.679 us; speedup vs baseline: 1.7901x; 1.0789x over previous
//
#include <hip/hip_runtime.h>
#include <hip/hip_bf16.h>
#include <math.h>

typedef short short8 __attribute__((ext_vector_type(8)));
typedef float f32x4  __attribute__((ext_vector_type(4)));

__device__ __forceinline__ unsigned short f2b(float f) {
  union { float f; unsigned int u; } x; x.f = f;
  return (unsigned short)((x.u + 0x7FFFu + ((x.u >> 16) & 1u)) >> 16);
}
__device__ __forceinline__ float b2f_u(unsigned short u) {
  union { unsigned int u; float f; } x; x.u = ((unsigned int)u) << 16;
  return x.f;
}
// packed f32x2 -> bf16x2 (v_cvt_pk_bf16_f32, RTNE)
__device__ __forceinline__ unsigned int pkbf(float a, float b) {
  union { __hip_bfloat162 h; unsigned int u; } c;
  c.h = __float22bfloat162_rn(make_float2(a, b));
  return c.u;
}
__device__ __forceinline__ float sigm(float x) {
  return __builtin_amdgcn_rcpf(1.f + __expf(-x));
}
__device__ __forceinline__ float tanhfast(float x) {
  float ax = fabsf(x);
  float em = __expf(-2.f * ax);
  float t  = (1.f - em) * __builtin_amdgcn_rcpf(1.f + em);
  return copysignf(t, x);
}
__device__ __forceinline__ float eluf(float v) {
  return v > 0.f ? v : (__expf(v) - 1.f);
}

// ---------------------------------------------------------------------------
// Prepack (unchanged).
// ---------------------------------------------------------------------------
__global__ __launch_bounds__(256) void prepack_kernel(
    const float* __restrict__ Wf,
    const float* __restrict__ Wc, const float* __restrict__ Wn,
    const float* __restrict__ as_c, const float* __restrict__ ad_c,
    const float* __restrict__ as_n, const float* __restrict__ ad_n,
    const float* __restrict__ Wproj,
    const float* __restrict__ Wih_f, const float* __restrict__ Wih_b,
    const float* __restrict__ Wout,
    const float* __restrict__ Whh_f, const float* __restrict__ Whh_b,
    unsigned short* __restrict__ fragB,
    unsigned short* __restrict__ fragWB,
    float* __restrict__ Wa,
    unsigned short* __restrict__ fragP,
    unsigned short* __restrict__ fragIH,
    unsigned short* __restrict__ fragO,
    unsigned short* __restrict__ fragHH)
{
  int e = blockIdx.x * 256 + threadIdx.x;
  unsigned short tmp[8];
  if (e < 4096) {
    int kb = e >> 9, tile = (e >> 6) & 7, lane = e & 63;
    int n = tile * 16 + (lane & 15);
    int kbase = kb * 32 + (lane >> 4) * 8;
#pragma unroll
    for (int j = 0; j < 8; j++) tmp[j] = f2b(Wf[(kbase + j) * 128 + n]);
    *(short8*)(fragB + e * 8) = *(short8*)tmp;
  } else if (e < 5120) {
    int i = e - 4096;
    int s = i >> 9, tile = (i >> 6) & 7, lane = i & 63;
    int c15 = lane & 15, quad = lane >> 4;
    int n = tile * 16 + c15;
    int h = n >> 5, o = n & 31;
    const float* W = s ? Wn : Wc;
#pragma unroll
    for (int j = 0; j < 8; j++) {
      int k = quad * 8 + j;
      tmp[j] = ((k >> 2) == h) ? f2b(W[h * 128 + (k & 3) * 32 + o])
                               : (unsigned short)0;
    }
    *(short8*)(fragWB + i * 8) = *(short8*)tmp;
  } else if (e < 5184) {
    int i = e - 5120;
    int s = i >> 5, d = (i >> 4) & 1, h = (i >> 2) & 3, f = i & 3;
    const float* W = s ? Wn : Wc;
    const float* a = s ? (d ? ad_n : as_n) : (d ? ad_c : as_c);
    float acc = 0.f;
#pragma unroll
    for (int o = 0; o < 32; o++) acc += W[h * 128 + f * 32 + o] * a[h * 32 + o];
    Wa[i] = acc;
  } else if (e < 6208) {
    int i = e - 5184;
    int kb = i >> 8, nt = (i >> 6) & 3, lane = i & 63;
    int c15 = lane & 15, quad = lane >> 4;
#pragma unroll
    for (int j = 0; j < 8; j++)
      tmp[j] = f2b(Wproj[(kb * 32 + quad * 8 + j) * 64 + nt * 16 + c15]);
    *(short8*)(fragP + i * 8) = *(short8*)tmp;
  } else if (e < 7744) {
    int i = e - 6208;
    int d = (i >= 768), r = i - d * 768;
    int kb = r / 384, nt = (r >> 6) % 6, lane = r & 63;
    int c15 = lane & 15, quad = lane >> 4;
    const float* W = d ? Wih_b : Wih_f;
#pragma unroll
    for (int j = 0; j < 8; j++)
      tmp[j] = f2b(W[(kb * 32 + quad * 8 + j) * 96 + nt * 16 + c15]);
    *(short8*)(fragIH + i * 8) = *(short8*)tmp;
  } else if (e < 9280) {
    int r = e - 7744;
    int kb = r >> 8, nt = (r >> 6) & 3, lane = r & 63;
    int c15 = lane & 15, quad = lane >> 4;
#pragma unroll
    for (int j = 0; j < 8; j++)
      tmp[j] = f2b(Wout[(kb * 32 + quad * 8 + j) * 64 + nt * 16 + c15]);
    *(short8*)(fragO + r * 8) = *(short8*)tmp;
  } else if (e < 10048) {
    int i = e - 9280;
    int d = i / 384, r = i - d * 384;
    int nt = r >> 6, lane = r & 63;
    int c15 = lane & 15, quad = lane >> 4;
    const float* W = d ? Whh_b : Whh_f;
#pragma unroll
    for (int j = 0; j < 8; j++)
      tmp[j] = f2b(W[(quad * 8 + j) * 96 + nt * 16 + c15]);
    *(short8*)(fragHH + i * 8) = *(short8*)tmp;
  }
}

// ---------------------------------------------------------------------------
// Kernel 1: GAT + fuse — SPATIAL dual-pair blocks. 512 threads = 8 waves;
// waves 0-3 process pair 0, waves 4-7 pair 1 (straight-line, NO loop -> VGPR
// stays r1-level). Halves block count (10240) and barriers-per-pair while
// keeping r1's proven occupancy regime (3 blocks/CU x 8 waves = 24 waves/CU
// ~= r1's 23). Wa and b_fuse hoisted to registers at init (kills sWa/sbias
// LDS + per-iter reads). Weights load per-use from L2 (r0/r1-proven).
// ---------------------------------------------------------------------------
__global__ __launch_bounds__(512) void gat_fuse_kernel(
    const float* __restrict__ self_f, const float* __restrict__ nbr_f,
    const float* __restrict__ Wa,
    const unsigned short* __restrict__ fragWB,
    const unsigned short* __restrict__ fragB,
    const float* __restrict__ b_fuse,
    unsigned short* __restrict__ embb,
    float* __restrict__ out,
    int npairs)
{
  const int tid = threadIdx.x;
  const int w = tid >> 6, lane = tid & 63, c15 = lane & 15, quad = lane >> 4;
  const int pr = w >> 2;          // pair slot within block (0/1)
  const int wq = w & 3;           // quadrant role within pair
  const int g_q = wq & 1, s_q = wq >> 1;
  const int ng  = pr * 2 + g_q;   // node slot within block (0..3)
  const int n0  = blockIdx.x * 4 + pr * 2;

  __shared__ __align__(16) float sxf[4][12][4];
  __shared__ float sed[4][2][4][12];
  __shared__ __align__(16) unsigned short sA[4][2][16][24];
  __shared__ __align__(16) unsigned short scatb[4][16][268];

  // ---- init: zero sA pad rows 12-15 (4 nodes x 2 streams x 4 rows x 12 dw) ----
  if (tid < 384) {
    int g4 = tid / 96, r = tid - g4 * 96;
    int s = r / 48, rr = r - s * 48;
    int row = 12 + rr / 12, cp = rr % 12;
    *(unsigned int*)&sA[g4][s][row][cp * 2] = 0u;
  }
  // ---- stage x: 4 nodes x 48 floats (48 lanes x f32x4) ----
  if (tid < 48) {
    int nd4 = tid / 12, q = tid - nd4 * 12;
    int nn = blockIdx.x * 4 + nd4, b = nn / 5, slot = nn - b * 5;
    const float* src = slot ? (nbr_f + (b * 4 + slot - 1) * 48)
                            : (self_f + b * 48);
    ((f32x4*)&sxf[nd4][0][0])[q] = *(const f32x4*)(src + q * 4);
  }
  // ---- per-lane constant registers (replace sWa / sbias LDS) ----
  f32x4 was, wad;
  {
    int hh = lane < 48 ? (lane / 12) : 3;
    was = *(const f32x4*)(Wa + s_q * 32 + hh * 4);
    wad = *(const f32x4*)(Wa + s_q * 32 + 16 + hh * 4);
  }
  const float bias0 = b_fuse[wq * 32 + c15];
  const float bias1 = b_fuse[wq * 32 + 16 + c15];
  // loop-invariant weight base pointers
  const unsigned short* __restrict__ pwb3 = fragWB + (s_q * 8 * 64 + lane) * 8;
  const unsigned short* __restrict__ pwb4 = fragB + (2 * wq * 64 + lane) * 8;

  __syncthreads();                             // barrier 1 (stage)

  // ---- phases 1+2 (wave-local softmax): lanes 0-47 of each wave ----
  if (lane < 48) {
    int h = lane / 12, i = lane - h * 12;
    f32x4 xv = *(const f32x4*)&sxf[ng][i][0];
    float es = xv[0]*was[0] + xv[1]*was[1] + xv[2]*was[2] + xv[3]*was[3];
    float ed = xv[0]*wad[0] + xv[1]*wad[1] + xv[2]*wad[2] + xv[3]*wad[3];
    sed[ng][s_q][h][i] = ed;
    int blk3 = (i / 3) * 3;
    float xa0 = 0.f, xa1 = 0.f, xa2 = 0.f, xa3 = 0.f, sum = 0.f;
    if (s_q == 0) {
#pragma unroll
      for (int jj = 0; jj < 3; jj++) {
        int j = blk3 + jj;
        float e = es + sed[ng][0][h][j];
        e = e > 0.f ? e : 0.2f * e;
        float p = __expf(e);
        sum += p;
        f32x4 xj = *(const f32x4*)&sxf[ng][j][0];
        xa0 += p * xj[0]; xa1 += p * xj[1];
        xa2 += p * xj[2]; xa3 += p * xj[3];
      }
    } else {
#pragma unroll
      for (int jj = 0; jj < 9; jj++) {
        int j = jj < blk3 ? jj : jj + 3;
        float e = es + sed[ng][1][h][j];
        e = e > 0.f ? e : 0.2f * e;
        float p = __expf(e);
        sum += p;
        f32x4 xj = *(const f32x4*)&sxf[ng][j][0];
        xa0 += p * xj[0]; xa1 += p * xj[1];
        xa2 += p * xj[2]; xa3 += p * xj[3];
      }
    }
    float inv = 1.f / sum;
    uint2 pk = make_uint2(pkbf(xa0 * inv, xa1 * inv),
                          pkbf(xa2 * inv, xa3 * inv));
    *(uint2*)&sA[ng][s_q][i][h * 4] = pk;
  }

  // ---- phase 3 (operand-swapped D^T; same wave consumes own (ng,s_q)) ----
  {
    const short8 z8 = {0,0,0,0,0,0,0,0};
    short8 xb = z8;
    if (quad < 2) xb = *(const short8*)&sA[ng][s_q][c15][quad * 8];
#pragma unroll
    for (int tile = 0; tile < 8; tile++) {
      short8 aw = *(const short8*)(pwb3 + tile * 512);
      f32x4 c = {0.f, 0.f, 0.f, 0.f};
      c = __builtin_amdgcn_mfma_f32_16x16x32_bf16(aw, xb, c, 0, 0, 0);
      uint2 pk = make_uint2(pkbf(eluf(c[0]), eluf(c[1])),
                            pkbf(eluf(c[2]), eluf(c[3])));
      *(uint2*)&scatb[ng][c15][s_q * 128 + tile * 16 + (quad << 2)] = pk;
    }
  }
  __syncthreads();                             // barrier 2 (scatb ready)

  // ---- phase 4: fuse GEMM; wave (pr,wq) covers N-tiles {2wq,2wq+1} of its pair ----
  {
    f32x4 acc[2][2];
#pragma unroll
    for (int nd = 0; nd < 2; nd++)
#pragma unroll
      for (int tt = 0; tt < 2; tt++) acc[nd][tt] = (f32x4){0.f,0.f,0.f,0.f};
#pragma unroll
    for (int kb = 0; kb < 8; kb++) {
      short8 a0 = *(const short8*)&scatb[pr * 2 + 0][c15][kb * 32 + (quad << 3)];
      short8 a1 = *(const short8*)&scatb[pr * 2 + 1][c15][kb * 32 + (quad << 3)];
#pragma unroll
      for (int tt = 0; tt < 2; tt++) {
        short8 bw = *(const short8*)(pwb4 + kb * 4096 + tt * 512);
        acc[0][tt] = __builtin_amdgcn_mfma_f32_16x16x32_bf16(a0, bw, acc[0][tt], 0, 0, 0);
        acc[1][tt] = __builtin_amdgcn_mfma_f32_16x16x32_bf16(a1, bw, acc[1][tt], 0, 0, 0);
      }
    }
    float tot[2][2];
#pragma unroll
    for (int nd = 0; nd < 2; nd++) {
#pragma unroll
      for (int tt = 0; tt < 2; tt++) {
        float p = 0.f;
        if (quad < 3) {
          float bcol = tt ? bias1 : bias0;
#pragma unroll
          for (int r = 0; r < 4; r++) p += eluf(acc[nd][tt][r] + bcol);
        }
        p += __shfl_xor(p, 16);
        p += __shfl_xor(p, 32);
        tot[nd][tt] = p;
      }
    }
    int ndw = quad >> 1, ttw = quad & 1;
    float val = (ndw ? (ttw ? tot[1][1] : tot[1][0])
                     : (ttw ? tot[0][1] : tot[0][0])) * (1.f / 12.f);
    int node = n0 + ndw;
    int col  = wq * 32 + ttw * 16 + c15;
    embb[node * 128 + col] = f2b(val);
    int bq = node / 5;
    if (node == bq * 5) out[bq * 192 + col] = val; // exact f32 passthrough
  }
}

// ---------------------------------------------------------------------------
// Kernel 2: head — unchanged (proven stable across r2/r5).
// ---------------------------------------------------------------------------
__global__ __launch_bounds__(256) void head_kernel(
    const unsigned short* __restrict__ embb,
    const float* __restrict__ maskp, const float* __restrict__ dirsp,
    const float* __restrict__ W_proj, const float* __restrict__ b_proj,
    const unsigned short* __restrict__ fragP,
    const unsigned short* __restrict__ fragIH,
    const unsigned short* __restrict__ fragHH,
    const float* __restrict__ bih_f, const float* __restrict__ bhh_f,
    const float* __restrict__ bih_b, const float* __restrict__ bhh_b,
    const unsigned short* __restrict__ fragO,
    const float* __restrict__ b_out,
    float* __restrict__ out)
{
  const int b8 = blockIdx.x * 8;
  const int tid = threadIdx.x;
  const int w = tid >> 6, lane = tid & 63, c15 = lane & 15, quad = lane >> 4;

  __shared__ __align__(16) unsigned short sX[32][72];
  __shared__ __align__(16) unsigned short sgi[2][32][96];
  __shared__ float sH[2][8][32];
  __shared__ __align__(16) unsigned short sHb[2][16][32];
  __shared__ __align__(16) float sgh[2][8][96];
  __shared__ __align__(16) unsigned short sCat[16][200];
  __shared__ __align__(16) float sPB[128];
  __shared__ __align__(16) float sBI[2][96], sBH[2][96];
  __shared__ __align__(16) float sBO[64];

  if (tid < 64) { sPB[tid] = b_proj[tid]; sPB[64 + tid] = W_proj[128 * 64 + tid]; sBO[tid] = b_out[tid]; }
  if (tid < 96) { sBI[0][tid] = bih_f[tid]; sBI[1][tid] = bih_b[tid];
                  sBH[0][tid] = bhh_f[tid]; sBH[1][tid] = bhh_b[tid]; }
  {
    unsigned int* hb = (unsigned int*)sHb;     // 512 dwords
    hb[tid] = 0u; hb[tid + 256] = 0u;
    float* hz = (float*)sH;
    for (int i = tid; i < 512; i += 256) hz[i] = 0.f;
  }
  __syncthreads();                             // B1

  // ---- proj via MFMA (swapped) ----
  {
    const int mt  = w >> 1;
    const int nt0 = (w & 1) * 2;
    const int sloc = mt * 4 + (c15 >> 2);
    const int nbr  = c15 & 3;
    const unsigned short* brow = embb + (((b8 + sloc) * 5) + 1 + nbr) * 128;
    short8 xb[4];
#pragma unroll
    for (int kb = 0; kb < 4; kb++)
      xb[kb] = *(const short8*)(brow + kb * 32 + quad * 8);
    f32x4 acc0 = {0.f,0.f,0.f,0.f}, acc1 = acc0;
#pragma unroll
    for (int kb = 0; kb < 4; kb++) {
      short8 a0 = *(const short8*)(fragP + ((kb * 4 + nt0    ) * 64 + lane) * 8);
      short8 a1 = *(const short8*)(fragP + ((kb * 4 + nt0 + 1) * 64 + lane) * 8);
      acc0 = __builtin_amdgcn_mfma_f32_16x16x32_bf16(a0, xb[kb], acc0, 0, 0, 0);
      acc1 = __builtin_amdgcn_mfma_f32_16x16x32_bf16(a1, xb[kb], acc1, 0, 0, 0);
    }
    const float dirv  = dirsp[(b8 + sloc) * 4 + nbr];
    const float maskv = maskp[(b8 + sloc) * 4 + nbr];
#pragma unroll
    for (int tt = 0; tt < 2; tt++) {
      f32x4 c = tt ? acc1 : acc0;
      int colb = (nt0 + tt) * 16 + (quad << 2);
      f32x4 wp = *(const f32x4*)&sPB[64 + colb];
      f32x4 pb = *(const f32x4*)&sPB[colb];
      float v0 = fmaxf(c[0] + dirv * wp[0] + pb[0], 0.f) * maskv;
      float v1 = fmaxf(c[1] + dirv * wp[1] + pb[1], 0.f) * maskv;
      float v2 = fmaxf(c[2] + dirv * wp[2] + pb[2], 0.f) * maskv;
      float v3 = fmaxf(c[3] + dirv * wp[3] + pb[3], 0.f) * maskv;
      uint2 pk = make_uint2(pkbf(v0, v1), pkbf(v2, v3));
      *(uint2*)&sX[mt * 16 + c15][colb] = pk;
    }
  }
  __syncthreads();                             // B2

  // ---- gi via MFMA + sCat self-emb staging ----
  {
    const int mt  = w >> 1;
    const int ntb = (w & 1) * 3;
    short8 xb0 = *(const short8*)&sX[mt * 16 + c15][quad * 8];
    short8 xb1 = *(const short8*)&sX[mt * 16 + c15][32 + quad * 8];
#pragma unroll
    for (int d = 0; d < 2; d++) {
#pragma unroll
      for (int t2 = 0; t2 < 3; t2++) {
        int nt = ntb + t2;
        f32x4 acc = {0.f,0.f,0.f,0.f};
        short8 a0 = *(const short8*)(fragIH + ((d * 12 +     nt) * 64 + lane) * 8);
        short8 a1 = *(const short8*)(fragIH + ((d * 12 + 6 + nt) * 64 + lane) * 8);
        acc = __builtin_amdgcn_mfma_f32_16x16x32_bf16(a0, xb0, acc, 0, 0, 0);
        acc = __builtin_amdgcn_mfma_f32_16x16x32_bf16(a1, xb1, acc, 0, 0, 0);
        f32x4 bi = *(const f32x4*)&sBI[d][nt * 16 + (quad << 2)];
        uint2 pk = make_uint2(pkbf(acc[0] + bi[0], acc[1] + bi[1]),
                              pkbf(acc[2] + bi[2], acc[3] + bi[3]));
        *(uint2*)&sgi[d][mt * 16 + c15][nt * 16 + (quad << 2)] = pk;
      }
    }
    if (tid >= 128) {                          // stage self_emb -> sCat[:,0:128]
      int t = tid - 128;                       // 0..127
      int s = t >> 4, c8 = (t & 15) * 8;
      short8 v = *(const short8*)(embb + (b8 + s) * 5 * 128 + c8);
      *(short8*)&sCat[s][c8] = v;
    }
  }
  __syncthreads();                             // B3

  // ---- GRU: 4 waves = (dir d = w>>1) x (sample-half q = w&1), 4 samples each.
  {
    const int d = w >> 1;
    const int q = w & 1;
    const int u = lane & 31, sp = lane >> 5;
    for (int step = 0; step < 4; step++) {
      short8 hb = *(const short8*)&sHb[d][c15][quad * 8];
#pragma unroll
      for (int nt = 0; nt < 6; nt++) {
        short8 aw = *(const short8*)(fragHH + ((d * 6 + nt) * 64 + lane) * 8);
        f32x4 c = {0.f,0.f,0.f,0.f};
        c = __builtin_amdgcn_mfma_f32_16x16x32_bf16(aw, hb, c, 0, 0, 0);
        if ((c15 >> 2) == q)                   // own sample rows only
          *(f32x4*)&sgh[d][c15][nt * 16 + (quad << 2)] = c;
      }
      const int k = d ? (3 - step) : step;
#pragma unroll
      for (int si = 0; si < 2; si++) {
        int s = q * 4 + sp + si * 2;
        int row = s * 4 + k;
        float ghr = sgh[d][s][u]      + sBH[d][u];
        float ghz = sgh[d][s][32 + u] + sBH[d][32 + u];
        float ghn = sgh[d][s][64 + u] + sBH[d][64 + u];
        float r = sigm(b2f_u(sgi[d][row][u]) + ghr);
        float z = sigm(b2f_u(sgi[d][row][32 + u]) + ghz);
        float n = tanhfast(b2f_u(sgi[d][row][64 + u]) + r * ghn);
        float h = (1.f - z) * n + z * sH[d][s][u];
        sH[d][s][u] = h;
        sHb[d][s][u] = f2b(h);
        if (step == 3) sCat[s][128 + d * 32 + u] = f2b(h);
      }
    }
  }
  __syncthreads();                             // B4

  // ---- out head via MFMA (swapped) ----
  {
    const int nt = w;
    f32x4 acc = {0.f,0.f,0.f,0.f};
#pragma unroll
    for (int kb = 0; kb < 6; kb++) {
      short8 bb = *(const short8*)&sCat[c15][kb * 32 + quad * 8];
      short8 aw = *(const short8*)(fragO + ((kb * 4 + nt) * 64 + lane) * 8);
      acc = __builtin_amdgcn_mfma_f32_16x16x32_bf16(aw, bb, acc, 0, 0, 0);
    }
    if (c15 < 8) {                             // D[out-col][sample]
      f32x4 bo = *(const f32x4*)&sBO[nt * 16 + (quad << 2)];
      f32x4 v;
      v[0] = fmaxf(acc[0] + bo[0], 0.f);
      v[1] = fmaxf(acc[1] + bo[1], 0.f);
      v[2] = fmaxf(acc[2] + bo[2], 0.f);
      v[3] = fmaxf(acc[3] + bo[3], 0.f);
      *(f32x4*)(out + (b8 + c15) * 192 + 128 + nt * 16 + (quad << 2)) = v;
    }
  }
}

// ---------------------------------------------------------------------------
extern "C" void kernel_launch(void* const* d_in, const int* in_sizes, int n_in,
                              void* d_out, int out_size, void* d_ws, size_t ws_size,
                              hipStream_t stream) {
  const float* self_f  = (const float*)d_in[0];
  const float* nbr_f   = (const float*)d_in[1];
  const float* maskp   = (const float*)d_in[2];
  const float* dirsp   = (const float*)d_in[3];
  const float* W_coop  = (const float*)d_in[4];
  const float* as_coop = (const float*)d_in[5];
  const float* ad_coop = (const float*)d_in[6];
  const float* W_conf  = (const float*)d_in[7];
  const float* as_conf = (const float*)d_in[8];
  const float* ad_conf = (const float*)d_in[9];
  const float* W_fuse  = (const float*)d_in[10];
  const float* b_fuse  = (const float*)d_in[11];
  const float* W_proj  = (const float*)d_in[12];
  const float* b_proj  = (const float*)d_in[13];
  const float* Wih_f   = (const float*)d_in[14];
  const float* Whh_f   = (const float*)d_in[15];
  const float* bih_f   = (const float*)d_in[16];
  const float* bhh_f   = (const float*)d_in[17];
  const float* Wih_b   = (const float*)d_in[18];
  const float* Whh_b   = (const float*)d_in[19];
  const float* bih_b   = (const float*)d_in[20];
  const float* bhh_b   = (const float*)d_in[21];
  const float* W_out   = (const float*)d_in[22];
  const float* b_out   = (const float*)d_in[23];

  const int B = in_sizes[0] / 48;   // 8192
  char* ws = (char*)d_ws;
  unsigned short* fragB  = (unsigned short*)(ws);            // 65536 B
  unsigned short* fragWB = (unsigned short*)(ws + 65536);    // 16384 B
  float*          Wa     = (float*)(ws + 81920);             // 256 B
  unsigned short* fragP  = (unsigned short*)(ws + 82176);    // 16384 B
  unsigned short* fragIH = (unsigned short*)(ws + 98560);    // 24576 B
  unsigned short* fragO  = (unsigned short*)(ws + 123136);   // 24576 B
  unsigned short* fragHH = (unsigned short*)(ws + 147712);   // 12288 B
  unsigned short* embb   = (unsigned short*)(ws + 160000);   // B*5*128*2

  prepack_kernel<<<40, 256, 0, stream>>>(
      W_fuse, W_coop, W_conf, as_coop, ad_coop, as_conf, ad_conf,
      W_proj, Wih_f, Wih_b, W_out, Whh_f, Whh_b,
      fragB, fragWB, Wa, fragP, fragIH, fragO, fragHH);

  const int npairs = B * 5 / 2;   // 20480
  gat_fuse_kernel<<<npairs / 2, 512, 0, stream>>>(
      self_f, nbr_f, Wa, fragWB, fragB, b_fuse, embb, (float*)d_out, npairs);

  head_kernel<<<B / 8, 256, 0, stream>>>(
      embb, maskp, dirsp, W_proj, b_proj, fragP, fragIH, fragHH,
      bih_f, bhh_f, bih_b, bhh_b,
      fragO, b_out, (float*)d_out);
}

// Round 7
// 220.705 us; speedup vs baseline: 1.8223x; 1.0180x over previous
//
#include <hip/hip_runtime.h>
#include <hip/hip_bf16.h>
#include <math.h>

typedef short short8 __attribute__((ext_vector_type(8)));
typedef float f32x4  __attribute__((ext_vector_type(4)));

__device__ __forceinline__ unsigned short f2b(float f) {
  union { float f; unsigned int u; } x; x.f = f;
  return (unsigned short)((x.u + 0x7FFFu + ((x.u >> 16) & 1u)) >> 16);
}
__device__ __forceinline__ float b2f_u(unsigned short u) {
  union { unsigned int u; float f; } x; x.u = ((unsigned int)u) << 16;
  return x.f;
}
// packed f32x2 -> bf16x2 (v_cvt_pk_bf16_f32, RTNE)
__device__ __forceinline__ unsigned int pkbf(float a, float b) {
  union { __hip_bfloat162 h; unsigned int u; } c;
  c.h = __float22bfloat162_rn(make_float2(a, b));
  return c.u;
}
__device__ __forceinline__ float sigm(float x) {
  return __builtin_amdgcn_rcpf(1.f + __expf(-x));
}
__device__ __forceinline__ float tanhfast(float x) {
  float ax = fabsf(x);
  float em = __expf(-2.f * ax);
  float t  = (1.f - em) * __builtin_amdgcn_rcpf(1.f + em);
  return copysignf(t, x);
}
__device__ __forceinline__ float eluf(float v) {
  return v > 0.f ? v : (__expf(v) - 1.f);
}

// ---------------------------------------------------------------------------
// Prepack (unchanged).
// ---------------------------------------------------------------------------
__global__ __launch_bounds__(256) void prepack_kernel(
    const float* __restrict__ Wf,
    const float* __restrict__ Wc, const float* __restrict__ Wn,
    const float* __restrict__ as_c, const float* __restrict__ ad_c,
    const float* __restrict__ as_n, const float* __restrict__ ad_n,
    const float* __restrict__ Wproj,
    const float* __restrict__ Wih_f, const float* __restrict__ Wih_b,
    const float* __restrict__ Wout,
    const float* __restrict__ Whh_f, const float* __restrict__ Whh_b,
    unsigned short* __restrict__ fragB,
    unsigned short* __restrict__ fragWB,
    float* __restrict__ Wa,
    unsigned short* __restrict__ fragP,
    unsigned short* __restrict__ fragIH,
    unsigned short* __restrict__ fragO,
    unsigned short* __restrict__ fragHH)
{
  int e = blockIdx.x * 256 + threadIdx.x;
  unsigned short tmp[8];
  if (e < 4096) {
    int kb = e >> 9, tile = (e >> 6) & 7, lane = e & 63;
    int n = tile * 16 + (lane & 15);
    int kbase = kb * 32 + (lane >> 4) * 8;
#pragma unroll
    for (int j = 0; j < 8; j++) tmp[j] = f2b(Wf[(kbase + j) * 128 + n]);
    *(short8*)(fragB + e * 8) = *(short8*)tmp;
  } else if (e < 5120) {
    int i = e - 4096;
    int s = i >> 9, tile = (i >> 6) & 7, lane = i & 63;
    int c15 = lane & 15, quad = lane >> 4;
    int n = tile * 16 + c15;
    int h = n >> 5, o = n & 31;
    const float* W = s ? Wn : Wc;
#pragma unroll
    for (int j = 0; j < 8; j++) {
      int k = quad * 8 + j;
      tmp[j] = ((k >> 2) == h) ? f2b(W[h * 128 + (k & 3) * 32 + o])
                               : (unsigned short)0;
    }
    *(short8*)(fragWB + i * 8) = *(short8*)tmp;
  } else if (e < 5184) {
    int i = e - 5120;
    int s = i >> 5, d = (i >> 4) & 1, h = (i >> 2) & 3, f = i & 3;
    const float* W = s ? Wn : Wc;
    const float* a = s ? (d ? ad_n : as_n) : (d ? ad_c : as_c);
    float acc = 0.f;
#pragma unroll
    for (int o = 0; o < 32; o++) acc += W[h * 128 + f * 32 + o] * a[h * 32 + o];
    Wa[i] = acc;
  } else if (e < 6208) {
    int i = e - 5184;
    int kb = i >> 8, nt = (i >> 6) & 3, lane = i & 63;
    int c15 = lane & 15, quad = lane >> 4;
#pragma unroll
    for (int j = 0; j < 8; j++)
      tmp[j] = f2b(Wproj[(kb * 32 + quad * 8 + j) * 64 + nt * 16 + c15]);
    *(short8*)(fragP + i * 8) = *(short8*)tmp;
  } else if (e < 7744) {
    int i = e - 6208;
    int d = (i >= 768), r = i - d * 768;
    int kb = r / 384, nt = (r >> 6) % 6, lane = r & 63;
    int c15 = lane & 15, quad = lane >> 4;
    const float* W = d ? Wih_b : Wih_f;
#pragma unroll
    for (int j = 0; j < 8; j++)
      tmp[j] = f2b(W[(kb * 32 + quad * 8 + j) * 96 + nt * 16 + c15]);
    *(short8*)(fragIH + i * 8) = *(short8*)tmp;
  } else if (e < 9280) {
    int r = e - 7744;
    int kb = r >> 8, nt = (r >> 6) & 3, lane = r & 63;
    int c15 = lane & 15, quad = lane >> 4;
#pragma unroll
    for (int j = 0; j < 8; j++)
      tmp[j] = f2b(Wout[(kb * 32 + quad * 8 + j) * 64 + nt * 16 + c15]);
    *(short8*)(fragO + r * 8) = *(short8*)tmp;
  } else if (e < 10048) {
    int i = e - 9280;
    int d = i / 384, r = i - d * 384;
    int nt = r >> 6, lane = r & 63;
    int c15 = lane & 15, quad = lane >> 4;
    const float* W = d ? Whh_b : Whh_f;
#pragma unroll
    for (int j = 0; j < 8; j++)
      tmp[j] = f2b(W[(quad * 8 + j) * 96 + nt * 16 + c15]);
    *(short8*)(fragHH + i * 8) = *(short8*)tmp;
  }
}

// ---------------------------------------------------------------------------
// Kernel 1: GAT + fuse — r6 spatial dual-pair structure. Changes this round:
// (a) sA pad rows 12-15 left UNINITIALIZED (their scatb rows feed only
//     discarded MFMA output rows — M rows don't mix, so garbage is harmless);
// (b) s_setprio(1) wraps both MFMA clusters (waves are phase-staggered by
//     the 3-vs-9 softmax imbalance -> scheduler can favor MFMA-entering
//     waves, T5 positive regime).
// ---------------------------------------------------------------------------
__global__ __launch_bounds__(512) void gat_fuse_kernel(
    const float* __restrict__ self_f, const float* __restrict__ nbr_f,
    const float* __restrict__ Wa,
    const unsigned short* __restrict__ fragWB,
    const unsigned short* __restrict__ fragB,
    const float* __restrict__ b_fuse,
    unsigned short* __restrict__ embb,
    float* __restrict__ out,
    int npairs)
{
  const int tid = threadIdx.x;
  const int w = tid >> 6, lane = tid & 63, c15 = lane & 15, quad = lane >> 4;
  const int pr = w >> 2;          // pair slot within block (0/1)
  const int wq = w & 3;           // quadrant role within pair
  const int g_q = wq & 1, s_q = wq >> 1;
  const int ng  = pr * 2 + g_q;   // node slot within block (0..3)
  const int n0  = blockIdx.x * 4 + pr * 2;

  __shared__ __align__(16) float sxf[4][12][4];
  __shared__ float sed[4][2][4][12];
  __shared__ __align__(16) unsigned short sA[4][2][16][24];
  __shared__ __align__(16) unsigned short scatb[4][16][268];

  // ---- stage x: 4 nodes x 48 floats (48 lanes x f32x4) ----
  if (tid < 48) {
    int nd4 = tid / 12, q = tid - nd4 * 12;
    int nn = blockIdx.x * 4 + nd4, b = nn / 5, slot = nn - b * 5;
    const float* src = slot ? (nbr_f + (b * 4 + slot - 1) * 48)
                            : (self_f + b * 48);
    ((f32x4*)&sxf[nd4][0][0])[q] = *(const f32x4*)(src + q * 4);
  }
  // ---- per-lane constant registers ----
  f32x4 was, wad;
  {
    int hh = lane < 48 ? (lane / 12) : 3;
    was = *(const f32x4*)(Wa + s_q * 32 + hh * 4);
    wad = *(const f32x4*)(Wa + s_q * 32 + 16 + hh * 4);
  }
  const float bias0 = b_fuse[wq * 32 + c15];
  const float bias1 = b_fuse[wq * 32 + 16 + c15];
  // loop-invariant weight base pointers
  const unsigned short* __restrict__ pwb3 = fragWB + (s_q * 8 * 64 + lane) * 8;
  const unsigned short* __restrict__ pwb4 = fragB + (2 * wq * 64 + lane) * 8;

  __syncthreads();                             // barrier 1 (stage)

  // ---- phases 1+2 (wave-local softmax): lanes 0-47 of each wave ----
  if (lane < 48) {
    int h = lane / 12, i = lane - h * 12;
    f32x4 xv = *(const f32x4*)&sxf[ng][i][0];
    float es = xv[0]*was[0] + xv[1]*was[1] + xv[2]*was[2] + xv[3]*was[3];
    float ed = xv[0]*wad[0] + xv[1]*wad[1] + xv[2]*wad[2] + xv[3]*wad[3];
    sed[ng][s_q][h][i] = ed;
    int blk3 = (i / 3) * 3;
    float xa0 = 0.f, xa1 = 0.f, xa2 = 0.f, xa3 = 0.f, sum = 0.f;
    if (s_q == 0) {
#pragma unroll
      for (int jj = 0; jj < 3; jj++) {
        int j = blk3 + jj;
        float e = es + sed[ng][0][h][j];
        e = e > 0.f ? e : 0.2f * e;
        float p = __expf(e);
        sum += p;
        f32x4 xj = *(const f32x4*)&sxf[ng][j][0];
        xa0 += p * xj[0]; xa1 += p * xj[1];
        xa2 += p * xj[2]; xa3 += p * xj[3];
      }
    } else {
#pragma unroll
      for (int jj = 0; jj < 9; jj++) {
        int j = jj < blk3 ? jj : jj + 3;
        float e = es + sed[ng][1][h][j];
        e = e > 0.f ? e : 0.2f * e;
        float p = __expf(e);
        sum += p;
        f32x4 xj = *(const f32x4*)&sxf[ng][j][0];
        xa0 += p * xj[0]; xa1 += p * xj[1];
        xa2 += p * xj[2]; xa3 += p * xj[3];
      }
    }
    float inv = 1.f / sum;
    uint2 pk = make_uint2(pkbf(xa0 * inv, xa1 * inv),
                          pkbf(xa2 * inv, xa3 * inv));
    *(uint2*)&sA[ng][s_q][i][h * 4] = pk;
  }

  // ---- phase 3 (operand-swapped D^T; same wave consumes own (ng,s_q)) ----
  {
    const short8 z8 = {0,0,0,0,0,0,0,0};
    short8 xb = z8;
    if (quad < 2) xb = *(const short8*)&sA[ng][s_q][c15][quad * 8];
    __builtin_amdgcn_s_setprio(1);
#pragma unroll
    for (int tile = 0; tile < 8; tile++) {
      short8 aw = *(const short8*)(pwb3 + tile * 512);
      f32x4 c = {0.f, 0.f, 0.f, 0.f};
      c = __builtin_amdgcn_mfma_f32_16x16x32_bf16(aw, xb, c, 0, 0, 0);
      uint2 pk = make_uint2(pkbf(eluf(c[0]), eluf(c[1])),
                            pkbf(eluf(c[2]), eluf(c[3])));
      *(uint2*)&scatb[ng][c15][s_q * 128 + tile * 16 + (quad << 2)] = pk;
    }
    __builtin_amdgcn_s_setprio(0);
  }
  __syncthreads();                             // barrier 2 (scatb ready)

  // ---- phase 4: fuse GEMM; wave (pr,wq) covers N-tiles {2wq,2wq+1} of its pair ----
  {
    f32x4 acc[2][2];
#pragma unroll
    for (int nd = 0; nd < 2; nd++)
#pragma unroll
      for (int tt = 0; tt < 2; tt++) acc[nd][tt] = (f32x4){0.f,0.f,0.f,0.f};
    __builtin_amdgcn_s_setprio(1);
#pragma unroll
    for (int kb = 0; kb < 8; kb++) {
      short8 a0 = *(const short8*)&scatb[pr * 2 + 0][c15][kb * 32 + (quad << 3)];
      short8 a1 = *(const short8*)&scatb[pr * 2 + 1][c15][kb * 32 + (quad << 3)];
#pragma unroll
      for (int tt = 0; tt < 2; tt++) {
        short8 bw = *(const short8*)(pwb4 + kb * 4096 + tt * 512);
        acc[0][tt] = __builtin_amdgcn_mfma_f32_16x16x32_bf16(a0, bw, acc[0][tt], 0, 0, 0);
        acc[1][tt] = __builtin_amdgcn_mfma_f32_16x16x32_bf16(a1, bw, acc[1][tt], 0, 0, 0);
      }
    }
    __builtin_amdgcn_s_setprio(0);
    float tot[2][2];
#pragma unroll
    for (int nd = 0; nd < 2; nd++) {
#pragma unroll
      for (int tt = 0; tt < 2; tt++) {
        float p = 0.f;
        if (quad < 3) {
          float bcol = tt ? bias1 : bias0;
#pragma unroll
          for (int r = 0; r < 4; r++) p += eluf(acc[nd][tt][r] + bcol);
        }
        p += __shfl_xor(p, 16);
        p += __shfl_xor(p, 32);
        tot[nd][tt] = p;
      }
    }
    int ndw = quad >> 1, ttw = quad & 1;
    float val = (ndw ? (ttw ? tot[1][1] : tot[1][0])
                     : (ttw ? tot[0][1] : tot[0][0])) * (1.f / 12.f);
    int node = n0 + ndw;
    int col  = wq * 32 + ttw * 16 + c15;
    embb[node * 128 + col] = f2b(val);
    int bq = node / 5;
    if (node == bq * 5) out[bq * 192 + col] = val; // exact f32 passthrough
  }
}

// ---------------------------------------------------------------------------
// Kernel 2: head — r6 structure; all global operand loads for the proj phase
// (embb fragments, fragP fragments, dir/mask) hoisted ABOVE the LDS-init
// barrier so their HBM/L2 latency overlaps init (compiler cannot hoist loads
// across __syncthreads itself).
// ---------------------------------------------------------------------------
__global__ __launch_bounds__(256) void head_kernel(
    const unsigned short* __restrict__ embb,
    const float* __restrict__ maskp, const float* __restrict__ dirsp,
    const float* __restrict__ W_proj, const float* __restrict__ b_proj,
    const unsigned short* __restrict__ fragP,
    const unsigned short* __restrict__ fragIH,
    const unsigned short* __restrict__ fragHH,
    const float* __restrict__ bih_f, const float* __restrict__ bhh_f,
    const float* __restrict__ bih_b, const float* __restrict__ bhh_b,
    const unsigned short* __restrict__ fragO,
    const float* __restrict__ b_out,
    float* __restrict__ out)
{
  const int b8 = blockIdx.x * 8;
  const int tid = threadIdx.x;
  const int w = tid >> 6, lane = tid & 63, c15 = lane & 15, quad = lane >> 4;

  __shared__ __align__(16) unsigned short sX[32][72];
  __shared__ __align__(16) unsigned short sgi[2][32][96];
  __shared__ float sH[2][8][32];
  __shared__ __align__(16) unsigned short sHb[2][16][32];
  __shared__ __align__(16) float sgh[2][8][96];
  __shared__ __align__(16) unsigned short sCat[16][200];
  __shared__ __align__(16) float sPB[128];
  __shared__ __align__(16) float sBI[2][96], sBH[2][96];
  __shared__ __align__(16) float sBO[64];

  // ---- proj operand loads issued BEFORE any LDS work (latency overlap) ----
  const int mt  = w >> 1;
  const int nt0 = (w & 1) * 2;
  const int sloc = mt * 4 + (c15 >> 2);
  const int nbr  = c15 & 3;
  const unsigned short* brow = embb + (((b8 + sloc) * 5) + 1 + nbr) * 128;
  short8 xb[4];
#pragma unroll
  for (int kb = 0; kb < 4; kb++)
    xb[kb] = *(const short8*)(brow + kb * 32 + quad * 8);
  short8 pa0[4], pa1[4];
#pragma unroll
  for (int kb = 0; kb < 4; kb++) {
    pa0[kb] = *(const short8*)(fragP + ((kb * 4 + nt0    ) * 64 + lane) * 8);
    pa1[kb] = *(const short8*)(fragP + ((kb * 4 + nt0 + 1) * 64 + lane) * 8);
  }
  const float dirv  = dirsp[(b8 + sloc) * 4 + nbr];
  const float maskv = maskp[(b8 + sloc) * 4 + nbr];

  if (tid < 64) { sPB[tid] = b_proj[tid]; sPB[64 + tid] = W_proj[128 * 64 + tid]; sBO[tid] = b_out[tid]; }
  if (tid < 96) { sBI[0][tid] = bih_f[tid]; sBI[1][tid] = bih_b[tid];
                  sBH[0][tid] = bhh_f[tid]; sBH[1][tid] = bhh_b[tid]; }
  {
    unsigned int* hb = (unsigned int*)sHb;     // 512 dwords
    hb[tid] = 0u; hb[tid + 256] = 0u;
    float* hz = (float*)sH;
    for (int i = tid; i < 512; i += 256) hz[i] = 0.f;
  }
  __syncthreads();                             // B1

  // ---- proj via MFMA (swapped; operands already in registers) ----
  {
    f32x4 acc0 = {0.f,0.f,0.f,0.f}, acc1 = acc0;
#pragma unroll
    for (int kb = 0; kb < 4; kb++) {
      acc0 = __builtin_amdgcn_mfma_f32_16x16x32_bf16(pa0[kb], xb[kb], acc0, 0, 0, 0);
      acc1 = __builtin_amdgcn_mfma_f32_16x16x32_bf16(pa1[kb], xb[kb], acc1, 0, 0, 0);
    }
#pragma unroll
    for (int tt = 0; tt < 2; tt++) {
      f32x4 c = tt ? acc1 : acc0;
      int colb = (nt0 + tt) * 16 + (quad << 2);
      f32x4 wp = *(const f32x4*)&sPB[64 + colb];
      f32x4 pb = *(const f32x4*)&sPB[colb];
      float v0 = fmaxf(c[0] + dirv * wp[0] + pb[0], 0.f) * maskv;
      float v1 = fmaxf(c[1] + dirv * wp[1] + pb[1], 0.f) * maskv;
      float v2 = fmaxf(c[2] + dirv * wp[2] + pb[2], 0.f) * maskv;
      float v3 = fmaxf(c[3] + dirv * wp[3] + pb[3], 0.f) * maskv;
      uint2 pk = make_uint2(pkbf(v0, v1), pkbf(v2, v3));
      *(uint2*)&sX[mt * 16 + c15][colb] = pk;
    }
  }
  __syncthreads();                             // B2

  // ---- gi via MFMA + sCat self-emb staging ----
  {
    const int ntb = (w & 1) * 3;
    short8 xb0 = *(const short8*)&sX[mt * 16 + c15][quad * 8];
    short8 xb1 = *(const short8*)&sX[mt * 16 + c15][32 + quad * 8];
#pragma unroll
    for (int d = 0; d < 2; d++) {
#pragma unroll
      for (int t2 = 0; t2 < 3; t2++) {
        int nt = ntb + t2;
        f32x4 acc = {0.f,0.f,0.f,0.f};
        short8 a0 = *(const short8*)(fragIH + ((d * 12 +     nt) * 64 + lane) * 8);
        short8 a1 = *(const short8*)(fragIH + ((d * 12 + 6 + nt) * 64 + lane) * 8);
        acc = __builtin_amdgcn_mfma_f32_16x16x32_bf16(a0, xb0, acc, 0, 0, 0);
        acc = __builtin_amdgcn_mfma_f32_16x16x32_bf16(a1, xb1, acc, 0, 0, 0);
        f32x4 bi = *(const f32x4*)&sBI[d][nt * 16 + (quad << 2)];
        uint2 pk = make_uint2(pkbf(acc[0] + bi[0], acc[1] + bi[1]),
                              pkbf(acc[2] + bi[2], acc[3] + bi[3]));
        *(uint2*)&sgi[d][mt * 16 + c15][nt * 16 + (quad << 2)] = pk;
      }
    }
    if (tid >= 128) {                          // stage self_emb -> sCat[:,0:128]
      int t = tid - 128;                       // 0..127
      int s = t >> 4, c8 = (t & 15) * 8;
      short8 v = *(const short8*)(embb + (b8 + s) * 5 * 128 + c8);
      *(short8*)&sCat[s][c8] = v;
    }
  }
  __syncthreads();                             // B3

  // ---- GRU: 4 waves = (dir d = w>>1) x (sample-half q = w&1), 4 samples each.
  {
    const int d = w >> 1;
    const int q = w & 1;
    const int u = lane & 31, sp = lane >> 5;
    for (int step = 0; step < 4; step++) {
      short8 hb = *(const short8*)&sHb[d][c15][quad * 8];
#pragma unroll
      for (int nt = 0; nt < 6; nt++) {
        short8 aw = *(const short8*)(fragHH + ((d * 6 + nt) * 64 + lane) * 8);
        f32x4 c = {0.f,0.f,0.f,0.f};
        c = __builtin_amdgcn_mfma_f32_16x16x32_bf16(aw, hb, c, 0, 0, 0);
        if ((c15 >> 2) == q)                   // own sample rows only
          *(f32x4*)&sgh[d][c15][nt * 16 + (quad << 2)] = c;
      }
      const int k = d ? (3 - step) : step;
#pragma unroll
      for (int si = 0; si < 2; si++) {
        int s = q * 4 + sp + si * 2;
        int row = s * 4 + k;
        float ghr = sgh[d][s][u]      + sBH[d][u];
        float ghz = sgh[d][s][32 + u] + sBH[d][32 + u];
        float ghn = sgh[d][s][64 + u] + sBH[d][64 + u];
        float r = sigm(b2f_u(sgi[d][row][u]) + ghr);
        float z = sigm(b2f_u(sgi[d][row][32 + u]) + ghz);
        float n = tanhfast(b2f_u(sgi[d][row][64 + u]) + r * ghn);
        float h = (1.f - z) * n + z * sH[d][s][u];
        sH[d][s][u] = h;
        sHb[d][s][u] = f2b(h);
        if (step == 3) sCat[s][128 + d * 32 + u] = f2b(h);
      }
    }
  }
  __syncthreads();                             // B4

  // ---- out head via MFMA (swapped) ----
  {
    const int nt = w;
    f32x4 acc = {0.f,0.f,0.f,0.f};
#pragma unroll
    for (int kb = 0; kb < 6; kb++) {
      short8 bb = *(const short8*)&sCat[c15][kb * 32 + quad * 8];
      short8 aw = *(const short8*)(fragO + ((kb * 4 + nt) * 64 + lane) * 8);
      acc = __builtin_amdgcn_mfma_f32_16x16x32_bf16(aw, bb, acc, 0, 0, 0);
    }
    if (c15 < 8) {                             // D[out-col][sample]
      f32x4 bo = *(const f32x4*)&sBO[nt * 16 + (quad << 2)];
      f32x4 v;
      v[0] = fmaxf(acc[0] + bo[0], 0.f);
      v[1] = fmaxf(acc[1] + bo[1], 0.f);
      v[2] = fmaxf(acc[2] + bo[2], 0.f);
      v[3] = fmaxf(acc[3] + bo[3], 0.f);
      *(f32x4*)(out + (b8 + c15) * 192 + 128 + nt * 16 + (quad << 2)) = v;
    }
  }
}

// ---------------------------------------------------------------------------
extern "C" void kernel_launch(void* const* d_in, const int* in_sizes, int n_in,
                              void* d_out, int out_size, void* d_ws, size_t ws_size,
                              hipStream_t stream) {
  const float* self_f  = (const float*)d_in[0];
  const float* nbr_f   = (const float*)d_in[1];
  const float* maskp   = (const float*)d_in[2];
  const float* dirsp   = (const float*)d_in[3];
  const float* W_coop  = (const float*)d_in[4];
  const float* as_coop = (const float*)d_in[5];
  const float* ad_coop = (const float*)d_in[6];
  const float* W_conf  = (const float*)d_in[7];
  const float* as_conf = (const float*)d_in[8];
  const float* ad_conf = (const float*)d_in[9];
  const float* W_fuse  = (const float*)d_in[10];
  const float* b_fuse  = (const float*)d_in[11];
  const float* W_proj  = (const float*)d_in[12];
  const float* b_proj  = (const float*)d_in[13];
  const float* Wih_f   = (const float*)d_in[14];
  const float* Whh_f   = (const float*)d_in[15];
  const float* bih_f   = (const float*)d_in[16];
  const float* bhh_f   = (const float*)d_in[17];
  const float* Wih_b   = (const float*)d_in[18];
  const float* Whh_b   = (const float*)d_in[19];
  const float* bih_b   = (const float*)d_in[20];
  const float* bhh_b   = (const float*)d_in[21];
  const float* W_out   = (const float*)d_in[22];
  const float* b_out   = (const float*)d_in[23];

  const int B = in_sizes[0] / 48;   // 8192
  char* ws = (char*)d_ws;
  unsigned short* fragB  = (unsigned short*)(ws);            // 65536 B
  unsigned short* fragWB = (unsigned short*)(ws + 65536);    // 16384 B
  float*          Wa     = (float*)(ws + 81920);             // 256 B
  unsigned short* fragP  = (unsigned short*)(ws + 82176);    // 16384 B
  unsigned short* fragIH = (unsigned short*)(ws + 98560);    // 24576 B
  unsigned short* fragO  = (unsigned short*)(ws + 123136);   // 24576 B
  unsigned short* fragHH = (unsigned short*)(ws + 147712);   // 12288 B
  unsigned short* embb   = (unsigned short*)(ws + 160000);   // B*5*128*2

  prepack_kernel<<<40, 256, 0, stream>>>(
      W_fuse, W_coop, W_conf, as_coop, ad_coop, as_conf, ad_conf,
      W_proj, Wih_f, Wih_b, W_out, Whh_f, Whh_b,
      fragB, fragWB, Wa, fragP, fragIH, fragO, fragHH);

  const int npairs = B * 5 / 2;   // 20480
  gat_fuse_kernel<<<npairs / 2, 512, 0, stream>>>(
      self_f, nbr_f, Wa, fragWB, fragB, b_fuse, embb, (float*)d_out, npairs);

  head_kernel<<<B / 8, 256, 0, stream>>>(
      embb, maskp, dirsp, W_proj, b_proj, fragP, fragIH, fragHH,
      bih_f, bhh_f, bih_b, bhh_b,
      fragO, b_out, (float*)d_out);
}

// Round 8
// 215.762 us; speedup vs baseline: 1.8641x; 1.0229x over previous
//
#include <hip/hip_runtime.h>
#include <hip/hip_bf16.h>
#include <math.h>

typedef short short8 __attribute__((ext_vector_type(8)));
typedef float f32x4  __attribute__((ext_vector_type(4)));

__device__ __forceinline__ unsigned short f2b(float f) {
  union { float f; unsigned int u; } x; x.f = f;
  return (unsigned short)((x.u + 0x7FFFu + ((x.u >> 16) & 1u)) >> 16);
}
__device__ __forceinline__ float b2f_u(unsigned short u) {
  union { unsigned int u; float f; } x; x.u = ((unsigned int)u) << 16;
  return x.f;
}
// packed f32x2 -> bf16x2 (v_cvt_pk_bf16_f32, RTNE)
__device__ __forceinline__ unsigned int pkbf(float a, float b) {
  union { __hip_bfloat162 h; unsigned int u; } c;
  c.h = __float22bfloat162_rn(make_float2(a, b));
  return c.u;
}
__device__ __forceinline__ float sigm(float x) {
  return __builtin_amdgcn_rcpf(1.f + __expf(-x));
}
__device__ __forceinline__ float tanhfast(float x) {
  float ax = fabsf(x);
  float em = __expf(-2.f * ax);
  float t  = (1.f - em) * __builtin_amdgcn_rcpf(1.f + em);
  return copysignf(t, x);
}
__device__ __forceinline__ float eluf(float v) {
  return v > 0.f ? v : (__expf(v) - 1.f);
}

// ---------------------------------------------------------------------------
// Prepack (unchanged).
// ---------------------------------------------------------------------------
__global__ __launch_bounds__(256) void prepack_kernel(
    const float* __restrict__ Wf,
    const float* __restrict__ Wc, const float* __restrict__ Wn,
    const float* __restrict__ as_c, const float* __restrict__ ad_c,
    const float* __restrict__ as_n, const float* __restrict__ ad_n,
    const float* __restrict__ Wproj,
    const float* __restrict__ Wih_f, const float* __restrict__ Wih_b,
    const float* __restrict__ Wout,
    const float* __restrict__ Whh_f, const float* __restrict__ Whh_b,
    unsigned short* __restrict__ fragB,
    unsigned short* __restrict__ fragWB,
    float* __restrict__ Wa,
    unsigned short* __restrict__ fragP,
    unsigned short* __restrict__ fragIH,
    unsigned short* __restrict__ fragO,
    unsigned short* __restrict__ fragHH)
{
  int e = blockIdx.x * 256 + threadIdx.x;
  unsigned short tmp[8];
  if (e < 4096) {
    int kb = e >> 9, tile = (e >> 6) & 7, lane = e & 63;
    int n = tile * 16 + (lane & 15);
    int kbase = kb * 32 + (lane >> 4) * 8;
#pragma unroll
    for (int j = 0; j < 8; j++) tmp[j] = f2b(Wf[(kbase + j) * 128 + n]);
    *(short8*)(fragB + e * 8) = *(short8*)tmp;
  } else if (e < 5120) {
    int i = e - 4096;
    int s = i >> 9, tile = (i >> 6) & 7, lane = i & 63;
    int c15 = lane & 15, quad = lane >> 4;
    int n = tile * 16 + c15;
    int h = n >> 5, o = n & 31;
    const float* W = s ? Wn : Wc;
#pragma unroll
    for (int j = 0; j < 8; j++) {
      int k = quad * 8 + j;
      tmp[j] = ((k >> 2) == h) ? f2b(W[h * 128 + (k & 3) * 32 + o])
                               : (unsigned short)0;
    }
    *(short8*)(fragWB + i * 8) = *(short8*)tmp;
  } else if (e < 5184) {
    int i = e - 5120;
    int s = i >> 5, d = (i >> 4) & 1, h = (i >> 2) & 3, f = i & 3;
    const float* W = s ? Wn : Wc;
    const float* a = s ? (d ? ad_n : as_n) : (d ? ad_c : as_c);
    float acc = 0.f;
#pragma unroll
    for (int o = 0; o < 32; o++) acc += W[h * 128 + f * 32 + o] * a[h * 32 + o];
    Wa[i] = acc;
  } else if (e < 6208) {
    int i = e - 5184;
    int kb = i >> 8, nt = (i >> 6) & 3, lane = i & 63;
    int c15 = lane & 15, quad = lane >> 4;
#pragma unroll
    for (int j = 0; j < 8; j++)
      tmp[j] = f2b(Wproj[(kb * 32 + quad * 8 + j) * 64 + nt * 16 + c15]);
    *(short8*)(fragP + i * 8) = *(short8*)tmp;
  } else if (e < 7744) {
    int i = e - 6208;
    int d = (i >= 768), r = i - d * 768;
    int kb = r / 384, nt = (r >> 6) % 6, lane = r & 63;
    int c15 = lane & 15, quad = lane >> 4;
    const float* W = d ? Wih_b : Wih_f;
#pragma unroll
    for (int j = 0; j < 8; j++)
      tmp[j] = f2b(W[(kb * 32 + quad * 8 + j) * 96 + nt * 16 + c15]);
    *(short8*)(fragIH + i * 8) = *(short8*)tmp;
  } else if (e < 9280) {
    int r = e - 7744;
    int kb = r >> 8, nt = (r >> 6) & 3, lane = r & 63;
    int c15 = lane & 15, quad = lane >> 4;
#pragma unroll
    for (int j = 0; j < 8; j++)
      tmp[j] = f2b(Wout[(kb * 32 + quad * 8 + j) * 64 + nt * 16 + c15]);
    *(short8*)(fragO + r * 8) = *(short8*)tmp;
  } else if (e < 10048) {
    int i = e - 9280;
    int d = i / 384, r = i - d * 384;
    int nt = r >> 6, lane = r & 63;
    int c15 = lane & 15, quad = lane >> 4;
    const float* W = d ? Whh_b : Whh_f;
#pragma unroll
    for (int j = 0; j < 8; j++)
      tmp[j] = f2b(W[(quad * 8 + j) * 96 + nt * 16 + c15]);
    *(short8*)(fragHH + i * 8) = *(short8*)tmp;
  }
}

// ---------------------------------------------------------------------------
// Kernel 1: GAT + fuse — r6 spatial dual-pair structure (setprio reverted:
// r7 showed a consistent +1.5us regression). sA pad rows uninitialized
// (feeds only discarded MFMA rows).
// ---------------------------------------------------------------------------
__global__ __launch_bounds__(512) void gat_fuse_kernel(
    const float* __restrict__ self_f, const float* __restrict__ nbr_f,
    const float* __restrict__ Wa,
    const unsigned short* __restrict__ fragWB,
    const unsigned short* __restrict__ fragB,
    const float* __restrict__ b_fuse,
    unsigned short* __restrict__ embb,
    float* __restrict__ out,
    int npairs)
{
  const int tid = threadIdx.x;
  const int w = tid >> 6, lane = tid & 63, c15 = lane & 15, quad = lane >> 4;
  const int pr = w >> 2;          // pair slot within block (0/1)
  const int wq = w & 3;           // quadrant role within pair
  const int g_q = wq & 1, s_q = wq >> 1;
  const int ng  = pr * 2 + g_q;   // node slot within block (0..3)
  const int n0  = blockIdx.x * 4 + pr * 2;

  __shared__ __align__(16) float sxf[4][12][4];
  __shared__ float sed[4][2][4][12];
  __shared__ __align__(16) unsigned short sA[4][2][16][24];
  __shared__ __align__(16) unsigned short scatb[4][16][268];

  // ---- stage x: 4 nodes x 48 floats (48 lanes x f32x4) ----
  if (tid < 48) {
    int nd4 = tid / 12, q = tid - nd4 * 12;
    int nn = blockIdx.x * 4 + nd4, b = nn / 5, slot = nn - b * 5;
    const float* src = slot ? (nbr_f + (b * 4 + slot - 1) * 48)
                            : (self_f + b * 48);
    ((f32x4*)&sxf[nd4][0][0])[q] = *(const f32x4*)(src + q * 4);
  }
  // ---- per-lane constant registers ----
  f32x4 was, wad;
  {
    int hh = lane < 48 ? (lane / 12) : 3;
    was = *(const f32x4*)(Wa + s_q * 32 + hh * 4);
    wad = *(const f32x4*)(Wa + s_q * 32 + 16 + hh * 4);
  }
  const float bias0 = b_fuse[wq * 32 + c15];
  const float bias1 = b_fuse[wq * 32 + 16 + c15];
  // loop-invariant weight base pointers
  const unsigned short* __restrict__ pwb3 = fragWB + (s_q * 8 * 64 + lane) * 8;
  const unsigned short* __restrict__ pwb4 = fragB + (2 * wq * 64 + lane) * 8;

  __syncthreads();                             // barrier 1 (stage)

  // ---- phases 1+2 (wave-local softmax): lanes 0-47 of each wave ----
  if (lane < 48) {
    int h = lane / 12, i = lane - h * 12;
    f32x4 xv = *(const f32x4*)&sxf[ng][i][0];
    float es = xv[0]*was[0] + xv[1]*was[1] + xv[2]*was[2] + xv[3]*was[3];
    float ed = xv[0]*wad[0] + xv[1]*wad[1] + xv[2]*wad[2] + xv[3]*wad[3];
    sed[ng][s_q][h][i] = ed;
    int blk3 = (i / 3) * 3;
    float xa0 = 0.f, xa1 = 0.f, xa2 = 0.f, xa3 = 0.f, sum = 0.f;
    if (s_q == 0) {
#pragma unroll
      for (int jj = 0; jj < 3; jj++) {
        int j = blk3 + jj;
        float e = es + sed[ng][0][h][j];
        e = e > 0.f ? e : 0.2f * e;
        float p = __expf(e);
        sum += p;
        f32x4 xj = *(const f32x4*)&sxf[ng][j][0];
        xa0 += p * xj[0]; xa1 += p * xj[1];
        xa2 += p * xj[2]; xa3 += p * xj[3];
      }
    } else {
#pragma unroll
      for (int jj = 0; jj < 9; jj++) {
        int j = jj < blk3 ? jj : jj + 3;
        float e = es + sed[ng][1][h][j];
        e = e > 0.f ? e : 0.2f * e;
        float p = __expf(e);
        sum += p;
        f32x4 xj = *(const f32x4*)&sxf[ng][j][0];
        xa0 += p * xj[0]; xa1 += p * xj[1];
        xa2 += p * xj[2]; xa3 += p * xj[3];
      }
    }
    float inv = 1.f / sum;
    uint2 pk = make_uint2(pkbf(xa0 * inv, xa1 * inv),
                          pkbf(xa2 * inv, xa3 * inv));
    *(uint2*)&sA[ng][s_q][i][h * 4] = pk;
  }

  // ---- phase 3 (operand-swapped D^T; same wave consumes own (ng,s_q)) ----
  {
    const short8 z8 = {0,0,0,0,0,0,0,0};
    short8 xb = z8;
    if (quad < 2) xb = *(const short8*)&sA[ng][s_q][c15][quad * 8];
#pragma unroll
    for (int tile = 0; tile < 8; tile++) {
      short8 aw = *(const short8*)(pwb3 + tile * 512);
      f32x4 c = {0.f, 0.f, 0.f, 0.f};
      c = __builtin_amdgcn_mfma_f32_16x16x32_bf16(aw, xb, c, 0, 0, 0);
      uint2 pk = make_uint2(pkbf(eluf(c[0]), eluf(c[1])),
                            pkbf(eluf(c[2]), eluf(c[3])));
      *(uint2*)&scatb[ng][c15][s_q * 128 + tile * 16 + (quad << 2)] = pk;
    }
  }
  __syncthreads();                             // barrier 2 (scatb ready)

  // ---- phase 4: fuse GEMM; wave (pr,wq) covers N-tiles {2wq,2wq+1} of its pair ----
  {
    f32x4 acc[2][2];
#pragma unroll
    for (int nd = 0; nd < 2; nd++)
#pragma unroll
      for (int tt = 0; tt < 2; tt++) acc[nd][tt] = (f32x4){0.f,0.f,0.f,0.f};
#pragma unroll
    for (int kb = 0; kb < 8; kb++) {
      short8 a0 = *(const short8*)&scatb[pr * 2 + 0][c15][kb * 32 + (quad << 3)];
      short8 a1 = *(const short8*)&scatb[pr * 2 + 1][c15][kb * 32 + (quad << 3)];
#pragma unroll
      for (int tt = 0; tt < 2; tt++) {
        short8 bw = *(const short8*)(pwb4 + kb * 4096 + tt * 512);
        acc[0][tt] = __builtin_amdgcn_mfma_f32_16x16x32_bf16(a0, bw, acc[0][tt], 0, 0, 0);
        acc[1][tt] = __builtin_amdgcn_mfma_f32_16x16x32_bf16(a1, bw, acc[1][tt], 0, 0, 0);
      }
    }
    float tot[2][2];
#pragma unroll
    for (int nd = 0; nd < 2; nd++) {
#pragma unroll
      for (int tt = 0; tt < 2; tt++) {
        float p = 0.f;
        if (quad < 3) {
          float bcol = tt ? bias1 : bias0;
#pragma unroll
          for (int r = 0; r < 4; r++) p += eluf(acc[nd][tt][r] + bcol);
        }
        p += __shfl_xor(p, 16);
        p += __shfl_xor(p, 32);
        tot[nd][tt] = p;
      }
    }
    int ndw = quad >> 1, ttw = quad & 1;
    float val = (ndw ? (ttw ? tot[1][1] : tot[1][0])
                     : (ttw ? tot[0][1] : tot[0][0])) * (1.f / 12.f);
    int node = n0 + ndw;
    int col  = wq * 32 + ttw * 16 + c15;
    embb[node * 128 + col] = f2b(val);
    int bq = node / 5;
    if (node == bq * 5) out[bq * 192 + col] = val; // exact f32 passthrough
  }
}

// ---------------------------------------------------------------------------
// Kernel 2: head. Changes this round:
// (a) GRU step 0 computed WITHOUT MFMA (h0=0 => gh=0): gates use bhh only,
//     h = (1-z)*n. Deletes 1 of 4 serial {ds->MFMA->ds->gates} rounds.
// (b) sH/sHb zero-init removed (step 0 never reads them; never-written sHb
//     rows feed only discarded MFMA columns).
// (c) fragO loads hoisted above B3 — latency hides under gi-tail + GRU.
// Proj operand pre-B1 hoist kept from r7 (-4us).
// ---------------------------------------------------------------------------
__global__ __launch_bounds__(256) void head_kernel(
    const unsigned short* __restrict__ embb,
    const float* __restrict__ maskp, const float* __restrict__ dirsp,
    const float* __restrict__ W_proj, const float* __restrict__ b_proj,
    const unsigned short* __restrict__ fragP,
    const unsigned short* __restrict__ fragIH,
    const unsigned short* __restrict__ fragHH,
    const float* __restrict__ bih_f, const float* __restrict__ bhh_f,
    const float* __restrict__ bih_b, const float* __restrict__ bhh_b,
    const unsigned short* __restrict__ fragO,
    const float* __restrict__ b_out,
    float* __restrict__ out)
{
  const int b8 = blockIdx.x * 8;
  const int tid = threadIdx.x;
  const int w = tid >> 6, lane = tid & 63, c15 = lane & 15, quad = lane >> 4;

  __shared__ __align__(16) unsigned short sX[32][72];
  __shared__ __align__(16) unsigned short sgi[2][32][96];
  __shared__ float sH[2][8][32];
  __shared__ __align__(16) unsigned short sHb[2][16][32];
  __shared__ __align__(16) float sgh[2][8][96];
  __shared__ __align__(16) unsigned short sCat[16][200];
  __shared__ __align__(16) float sPB[128];
  __shared__ __align__(16) float sBI[2][96], sBH[2][96];
  __shared__ __align__(16) float sBO[64];

  // ---- proj operand loads issued BEFORE any LDS work (latency overlap) ----
  const int mt  = w >> 1;
  const int nt0 = (w & 1) * 2;
  const int sloc = mt * 4 + (c15 >> 2);
  const int nbr  = c15 & 3;
  const unsigned short* brow = embb + (((b8 + sloc) * 5) + 1 + nbr) * 128;
  short8 xb[4];
#pragma unroll
  for (int kb = 0; kb < 4; kb++)
    xb[kb] = *(const short8*)(brow + kb * 32 + quad * 8);
  short8 pa0[4], pa1[4];
#pragma unroll
  for (int kb = 0; kb < 4; kb++) {
    pa0[kb] = *(const short8*)(fragP + ((kb * 4 + nt0    ) * 64 + lane) * 8);
    pa1[kb] = *(const short8*)(fragP + ((kb * 4 + nt0 + 1) * 64 + lane) * 8);
  }
  const float dirv  = dirsp[(b8 + sloc) * 4 + nbr];
  const float maskv = maskp[(b8 + sloc) * 4 + nbr];

  if (tid < 64) { sPB[tid] = b_proj[tid]; sPB[64 + tid] = W_proj[128 * 64 + tid]; sBO[tid] = b_out[tid]; }
  if (tid < 96) { sBI[0][tid] = bih_f[tid]; sBI[1][tid] = bih_b[tid];
                  sBH[0][tid] = bhh_f[tid]; sBH[1][tid] = bhh_b[tid]; }
  __syncthreads();                             // B1

  // ---- proj via MFMA (swapped; operands already in registers) ----
  {
    f32x4 acc0 = {0.f,0.f,0.f,0.f}, acc1 = acc0;
#pragma unroll
    for (int kb = 0; kb < 4; kb++) {
      acc0 = __builtin_amdgcn_mfma_f32_16x16x32_bf16(pa0[kb], xb[kb], acc0, 0, 0, 0);
      acc1 = __builtin_amdgcn_mfma_f32_16x16x32_bf16(pa1[kb], xb[kb], acc1, 0, 0, 0);
    }
#pragma unroll
    for (int tt = 0; tt < 2; tt++) {
      f32x4 c = tt ? acc1 : acc0;
      int colb = (nt0 + tt) * 16 + (quad << 2);
      f32x4 wp = *(const f32x4*)&sPB[64 + colb];
      f32x4 pb = *(const f32x4*)&sPB[colb];
      float v0 = fmaxf(c[0] + dirv * wp[0] + pb[0], 0.f) * maskv;
      float v1 = fmaxf(c[1] + dirv * wp[1] + pb[1], 0.f) * maskv;
      float v2 = fmaxf(c[2] + dirv * wp[2] + pb[2], 0.f) * maskv;
      float v3 = fmaxf(c[3] + dirv * wp[3] + pb[3], 0.f) * maskv;
      uint2 pk = make_uint2(pkbf(v0, v1), pkbf(v2, v3));
      *(uint2*)&sX[mt * 16 + c15][colb] = pk;
    }
  }
  __syncthreads();                             // B2

  // ---- gi via MFMA + sCat self-emb staging ----
  {
    const int ntb = (w & 1) * 3;
    short8 xb0 = *(const short8*)&sX[mt * 16 + c15][quad * 8];
    short8 xb1 = *(const short8*)&sX[mt * 16 + c15][32 + quad * 8];
#pragma unroll
    for (int d = 0; d < 2; d++) {
#pragma unroll
      for (int t2 = 0; t2 < 3; t2++) {
        int nt = ntb + t2;
        f32x4 acc = {0.f,0.f,0.f,0.f};
        short8 a0 = *(const short8*)(fragIH + ((d * 12 +     nt) * 64 + lane) * 8);
        short8 a1 = *(const short8*)(fragIH + ((d * 12 + 6 + nt) * 64 + lane) * 8);
        acc = __builtin_amdgcn_mfma_f32_16x16x32_bf16(a0, xb0, acc, 0, 0, 0);
        acc = __builtin_amdgcn_mfma_f32_16x16x32_bf16(a1, xb1, acc, 0, 0, 0);
        f32x4 bi = *(const f32x4*)&sBI[d][nt * 16 + (quad << 2)];
        uint2 pk = make_uint2(pkbf(acc[0] + bi[0], acc[1] + bi[1]),
                              pkbf(acc[2] + bi[2], acc[3] + bi[3]));
        *(uint2*)&sgi[d][mt * 16 + c15][nt * 16 + (quad << 2)] = pk;
      }
    }
    if (tid >= 128) {                          // stage self_emb -> sCat[:,0:128]
      int t = tid - 128;                       // 0..127
      int s = t >> 4, c8 = (t & 15) * 8;
      short8 v = *(const short8*)(embb + (b8 + s) * 5 * 128 + c8);
      *(short8*)&sCat[s][c8] = v;
    }
  }
  // ---- fragO loads hoisted here: latency hides under gi-tail + GRU ----
  short8 ao[6];
#pragma unroll
  for (int kb = 0; kb < 6; kb++)
    ao[kb] = *(const short8*)(fragO + ((kb * 4 + w) * 64 + lane) * 8);
  __syncthreads();                             // B3

  // ---- GRU: 4 waves = (dir d = w>>1) x (sample-half q = w&1), 4 samples each.
  {
    const int d = w >> 1;
    const int q = w & 1;
    const int u = lane & 31, sp = lane >> 5;
    // step 0: h=0 => gh=0. No MFMA, no sgh, no sH/sHb reads.
    {
      const int k0 = d ? 3 : 0;
      const float bhr = sBH[d][u], bhz = sBH[d][32 + u], bhn = sBH[d][64 + u];
#pragma unroll
      for (int si = 0; si < 2; si++) {
        int s = q * 4 + sp + si * 2;
        int row = s * 4 + k0;
        float r = sigm(b2f_u(sgi[d][row][u]) + bhr);
        float z = sigm(b2f_u(sgi[d][row][32 + u]) + bhz);
        float n = tanhfast(b2f_u(sgi[d][row][64 + u]) + r * bhn);
        float h = (1.f - z) * n;
        sH[d][s][u] = h;
        sHb[d][s][u] = f2b(h);
      }
    }
    for (int step = 1; step < 4; step++) {
      short8 hb = *(const short8*)&sHb[d][c15][quad * 8];
#pragma unroll
      for (int nt = 0; nt < 6; nt++) {
        short8 aw = *(const short8*)(fragHH + ((d * 6 + nt) * 64 + lane) * 8);
        f32x4 c = {0.f,0.f,0.f,0.f};
        c = __builtin_amdgcn_mfma_f32_16x16x32_bf16(aw, hb, c, 0, 0, 0);
        if ((c15 >> 2) == q)                   // own sample rows only
          *(f32x4*)&sgh[d][c15][nt * 16 + (quad << 2)] = c;
      }
      const int k = d ? (3 - step) : step;
#pragma unroll
      for (int si = 0; si < 2; si++) {
        int s = q * 4 + sp + si * 2;
        int row = s * 4 + k;
        float ghr = sgh[d][s][u]      + sBH[d][u];
        float ghz = sgh[d][s][32 + u] + sBH[d][32 + u];
        float ghn = sgh[d][s][64 + u] + sBH[d][64 + u];
        float r = sigm(b2f_u(sgi[d][row][u]) + ghr);
        float z = sigm(b2f_u(sgi[d][row][32 + u]) + ghz);
        float n = tanhfast(b2f_u(sgi[d][row][64 + u]) + r * ghn);
        float h = (1.f - z) * n + z * sH[d][s][u];
        sH[d][s][u] = h;
        sHb[d][s][u] = f2b(h);
        if (step == 3) sCat[s][128 + d * 32 + u] = f2b(h);
      }
    }
  }
  __syncthreads();                             // B4

  // ---- out head via MFMA (swapped; A operands already in registers) ----
  {
    const int nt = w;
    f32x4 acc = {0.f,0.f,0.f,0.f};
#pragma unroll
    for (int kb = 0; kb < 6; kb++) {
      short8 bb = *(const short8*)&sCat[c15][kb * 32 + quad * 8];
      acc = __builtin_amdgcn_mfma_f32_16x16x32_bf16(ao[kb], bb, acc, 0, 0, 0);
    }
    if (c15 < 8) {                             // D[out-col][sample]
      f32x4 bo = *(const f32x4*)&sBO[nt * 16 + (quad << 2)];
      f32x4 v;
      v[0] = fmaxf(acc[0] + bo[0], 0.f);
      v[1] = fmaxf(acc[1] + bo[1], 0.f);
      v[2] = fmaxf(acc[2] + bo[2], 0.f);
      v[3] = fmaxf(acc[3] + bo[3], 0.f);
      *(f32x4*)(out + (b8 + c15) * 192 + 128 + nt * 16 + (quad << 2)) = v;
    }
  }
}

// ---------------------------------------------------------------------------
extern "C" void kernel_launch(void* const* d_in, const int* in_sizes, int n_in,
                              void* d_out, int out_size, void* d_ws, size_t ws_size,
                              hipStream_t stream) {
  const float* self_f  = (const float*)d_in[0];
  const float* nbr_f   = (const float*)d_in[1];
  const float* maskp   = (const float*)d_in[2];
  const float* dirsp   = (const float*)d_in[3];
  const float* W_coop  = (const float*)d_in[4];
  const float* as_coop = (const float*)d_in[5];
  const float* ad_coop = (const float*)d_in[6];
  const float* W_conf  = (const float*)d_in[7];
  const float* as_conf = (const float*)d_in[8];
  const float* ad_conf = (const float*)d_in[9];
  const float* W_fuse  = (const float*)d_in[10];
  const float* b_fuse  = (const float*)d_in[11];
  const float* W_proj  = (const float*)d_in[12];
  const float* b_proj  = (const float*)d_in[13];
  const float* Wih_f   = (const float*)d_in[14];
  const float* Whh_f   = (const float*)d_in[15];
  const float* bih_f   = (const float*)d_in[16];
  const float* bhh_f   = (const float*)d_in[17];
  const float* Wih_b   = (const float*)d_in[18];
  const float* Whh_b   = (const float*)d_in[19];
  const float* bih_b   = (const float*)d_in[20];
  const float* bhh_b   = (const float*)d_in[21];
  const float* W_out   = (const float*)d_in[22];
  const float* b_out   = (const float*)d_in[23];

  const int B = in_sizes[0] / 48;   // 8192
  char* ws = (char*)d_ws;
  unsigned short* fragB  = (unsigned short*)(ws);            // 65536 B
  unsigned short* fragWB = (unsigned short*)(ws + 65536);    // 16384 B
  float*          Wa     = (float*)(ws + 81920);             // 256 B
  unsigned short* fragP  = (unsigned short*)(ws + 82176);    // 16384 B
  unsigned short* fragIH = (unsigned short*)(ws + 98560);    // 24576 B
  unsigned short* fragO  = (unsigned short*)(ws + 123136);   // 24576 B
  unsigned short* fragHH = (unsigned short*)(ws + 147712);   // 12288 B
  unsigned short* embb   = (unsigned short*)(ws + 160000);   // B*5*128*2

  prepack_kernel<<<40, 256, 0, stream>>>(
      W_fuse, W_coop, W_conf, as_coop, ad_coop, as_conf, ad_conf,
      W_proj, Wih_f, Wih_b, W_out, Whh_f, Whh_b,
      fragB, fragWB, Wa, fragP, fragIH, fragO, fragHH);

  const int npairs = B * 5 / 2;   // 20480
  gat_fuse_kernel<<<npairs / 2, 512, 0, stream>>>(
      self_f, nbr_f, Wa, fragWB, fragB, b_fuse, embb, (float*)d_out, npairs);

  head_kernel<<<B / 8, 256, 0, stream>>>(
      embb, maskp, dirsp, W_proj, b_proj, fragP, fragIH, fragHH,
      bih_f, bhh_f, bih_b, bhh_b,
      fragO, b_out, (float*)d_out);
}